// Round 1
// baseline (15059.561 us; speedup 1.0000x reference)
//
#include <hip/hip_runtime.h>

#define LB __launch_bounds__(256)

constexpr int S = 19;

__device__ __forceinline__ int reflect256(int i) { return i < 0 ? -i : (i > 255 ? 510 - i : i); }

// ---------------- conv1: [8,3,256,256] -> [8,32,256,256], reflect pad 1 ----------------
__global__ LB void k_conv1(const float* __restrict__ in, const float* __restrict__ w,
                           const float* __restrict__ bias, float* __restrict__ out) {
    int idx = blockIdx.x * 256 + threadIdx.x;
    int x = idx & 255, y = (idx >> 8) & 255, co = (idx >> 16) & 31, b = idx >> 21;
    float acc = bias[co];
    for (int ci = 0; ci < 3; ++ci) {
        const float* ip = in + ((b * 3 + ci) << 16);
        const float* wp = w + (co * 3 + ci) * 9;
        #pragma unroll
        for (int ky = 0; ky < 3; ++ky) {
            int iy = reflect256(y + ky - 1);
            #pragma unroll
            for (int kx = 0; kx < 3; ++kx) {
                int ix = reflect256(x + kx - 1);
                acc += ip[(iy << 8) + ix] * wp[ky * 3 + kx];
            }
        }
    }
    out[idx] = acc;
}

// ---------------- instance-norm stats: one block per (b,c) ----------------
__global__ LB void k_instats(const float* __restrict__ x, int HW,
                             float* __restrict__ mean, float* __restrict__ istd) {
    int bc = blockIdx.x;
    const float4* p = (const float4*)(x + (long)bc * HW);
    int n4 = HW >> 2;
    float s = 0.f, ss = 0.f;
    for (int i = threadIdx.x; i < n4; i += 256) {
        float4 v = p[i];
        s += v.x + v.y + v.z + v.w;
        ss += v.x * v.x + v.y * v.y + v.z * v.z + v.w * v.w;
    }
    #pragma unroll
    for (int o = 32; o > 0; o >>= 1) { s += __shfl_down(s, o); ss += __shfl_down(ss, o); }
    __shared__ float ls[4], lss[4];
    int wid = threadIdx.x >> 6;
    if ((threadIdx.x & 63) == 0) { ls[wid] = s; lss[wid] = ss; }
    __syncthreads();
    if (threadIdx.x == 0) {
        s = ls[0] + ls[1] + ls[2] + ls[3];
        ss = lss[0] + lss[1] + lss[2] + lss[3];
        float m = s / (float)HW;
        float v = ss / (float)HW - m * m;
        mean[bc] = m;
        istd[bc] = rsqrtf(v + 1e-5f);
    }
}

// ---------------- normalize + leaky-relu, in place, float4 ----------------
__global__ LB void k_normlrelu(float* __restrict__ x, int HW,
                               const float* __restrict__ mean, const float* __restrict__ istd) {
    long i = (long)blockIdx.x * 256 + threadIdx.x;   // index in float4 units
    int bc = (int)((i << 2) / HW);
    float m = mean[bc], is = istd[bc];
    float4* p = (float4*)x;
    float4 v = p[i];
    float t0 = (v.x - m) * is; v.x = t0 > 0.f ? t0 : 0.2f * t0;
    float t1 = (v.y - m) * is; v.y = t1 > 0.f ? t1 : 0.2f * t1;
    float t2 = (v.z - m) * is; v.z = t2 > 0.f ? t2 : 0.2f * t2;
    float t3 = (v.w - m) * is; v.w = t3 > 0.f ? t3 : 0.2f * t3;
    p[i] = v;
}

// ---------------- strided conv 3x3 s2 p1 (zero pad) ----------------
template <int CIN, int COUT, int HIN>
__global__ LB void k_conv_s2(const float* __restrict__ in, const float* __restrict__ w,
                             const float* __restrict__ bias, float* __restrict__ out) {
    constexpr int HOUT = HIN / 2;
    int idx = blockIdx.x * 256 + threadIdx.x;
    int x = idx % HOUT;
    int t = idx / HOUT;
    int y = t % HOUT; t /= HOUT;
    int co = t % COUT;
    int b = t / COUT;
    float acc = bias[co];
    const float* wbase = w + co * CIN * 9;
    #pragma unroll 4
    for (int ci = 0; ci < CIN; ++ci) {
        const float* ip = in + (long)(b * CIN + ci) * HIN * HIN;
        const float* wp = wbase + ci * 9;
        #pragma unroll
        for (int ky = 0; ky < 3; ++ky) {
            int iy = 2 * y + ky - 1;
            if (iy < 0 || iy >= HIN) continue;
            #pragma unroll
            for (int kx = 0; kx < 3; ++kx) {
                int ix = 2 * x + kx - 1;
                if (ix < 0 || ix >= HIN) continue;
                acc += ip[iy * HIN + ix] * wp[ky * 3 + kx];
            }
        }
    }
    out[idx] = acc;
}

// ---------------- conv-transpose: [8,128,64,64] -> [8,256,128,128], k3 s2 p1 op1 ----------------
__global__ LB void k_convt4(const float* __restrict__ in, const float* __restrict__ w,
                            const float* __restrict__ bias, float* __restrict__ out) {
    int idx = blockIdx.x * 256 + threadIdx.x;
    int x = idx & 127, y = (idx >> 7) & 127, co = (idx >> 14) & 255, b = idx >> 22;
    float acc = bias[co];
    #pragma unroll
    for (int ky = 0; ky < 3; ++ky) {
        int yy = y + 1 - ky;
        if (yy & 1) continue;          // negative yy (=-1) is odd -> skipped
        int i = yy >> 1;
        if (i >= 64) continue;
        #pragma unroll
        for (int kx = 0; kx < 3; ++kx) {
            int xx = x + 1 - kx;
            if (xx & 1) continue;
            int j = xx >> 1;
            if (j >= 64) continue;
            const float* wp = w + (co * 3 + ky) * 3 + kx;   // + ci*2304
            const float* ip = in + ((b * 128) << 12) + (i << 6) + j;  // + ci*4096
            float a = 0.f;
            #pragma unroll 4
            for (int ci = 0; ci < 128; ++ci)
                a += ip[ci << 12] * wp[ci * 2304];
            acc += a;
        }
    }
    out[idx] = acc;
}

// ---------------- label map @128x128 (nearest = even subsample) + per-class counts ----------------
__global__ LB void k_label(const float* __restrict__ segmap, int* __restrict__ lab,
                           int* __restrict__ counts) {
    __shared__ int h[S];
    if (threadIdx.x < S) h[threadIdx.x] = 0;
    __syncthreads();
    int idx = blockIdx.x * 256 + threadIdx.x;        // 8*128*128
    int x = idx & 127, y = (idx >> 7) & 127, b = idx >> 14;
    const float* sp = segmap + (long)b * S * 65536 + (y << 1) * 256 + (x << 1);
    int s = 0;
    for (int c = 0; c < S; ++c) {
        if (sp[c * 65536] > 0.f) { s = c; break; }
    }
    lab[idx] = s;
    atomicAdd(&h[s], 1);
    __syncthreads();
    if (threadIdx.x < S) atomicAdd(&counts[b * S + threadIdx.x], h[threadIdx.x]);
}

// ---------------- conv5 (reflect pad, 256->512 @128^2) + bias + tanh + masked class-sum ----------------
// tile: 64 cout x (32 rows x 8 cols) positions, per-thread 8co x 8pos, K-chunks of 8 ci
__global__ LB void k_conv5(const float* __restrict__ in, const float* __restrict__ w,
                           const float* __restrict__ bias, const int* __restrict__ lab,
                           float* __restrict__ sumbuf) {
    __shared__ float As[8 * 34 * 10];   // [ci][row 34][col 10]
    __shared__ float Ws[64 * 73];       // [co][ci*9+k], stride 73 (pad for banks)
    __shared__ float part[S * 64];
    int bx = blockIdx.x;
    int b = bx >> 9;
    int r = bx & 511;
    int ct = r >> 6;          // cout tile 0..7
    int pt = r & 63;          // position tile
    int ty = pt >> 4, tx = pt & 15;
    int y0 = ty * 32, x0 = tx * 8, co0 = ct * 64;
    int t = threadIdx.x;
    int cog = t & 7;          // co group: co_l = cog*8 + cc
    int pg = t >> 3;          // row 0..31

    float acc[8][8];
    #pragma unroll
    for (int a = 0; a < 8; ++a)
        #pragma unroll
        for (int c = 0; c < 8; ++c) acc[a][c] = 0.f;

    for (int ci0 = 0; ci0 < 256; ci0 += 8) {
        // stage input patch 34x10 x 8ci with reflect pad
        for (int e = t; e < 2720; e += 256) {
            int ci = e / 340; int rem = e - ci * 340;
            int iy = rem / 10; int ix = rem - iy * 10;
            int gy = y0 - 1 + iy; gy = gy < 0 ? -gy : (gy > 127 ? 254 - gy : gy);
            int gx = x0 - 1 + ix; gx = gx < 0 ? -gx : (gx > 127 ? 254 - gx : gx);
            As[e] = in[(((long)(b * 256 + ci0 + ci)) << 14) + (gy << 7) + gx];
        }
        // stage weights 64co x 8ci x 9
        for (int e = t; e < 4608; e += 256) {
            int co_l = e / 72; int rr = e - co_l * 72;
            Ws[co_l * 73 + rr] = w[(co0 + co_l) * 2304 + ci0 * 9 + rr];
        }
        __syncthreads();
        const float* wrow = &Ws[(cog * 8) * 73];
        #pragma unroll
        for (int ci = 0; ci < 8; ++ci) {
            #pragma unroll
            for (int ky = 0; ky < 3; ++ky) {
                #pragma unroll
                for (int kx = 0; kx < 3; ++kx) {
                    int kk = ci * 9 + ky * 3 + kx;
                    float wv[8], av[8];
                    #pragma unroll
                    for (int cc = 0; cc < 8; ++cc) wv[cc] = wrow[cc * 73 + kk];
                    #pragma unroll
                    for (int c8 = 0; c8 < 8; ++c8) av[c8] = As[ci * 340 + (pg + ky) * 10 + kx + c8];
                    #pragma unroll
                    for (int cc = 0; cc < 8; ++cc)
                        #pragma unroll
                        for (int c8 = 0; c8 < 8; ++c8)
                            acc[cc][c8] += wv[cc] * av[c8];
                }
            }
        }
        __syncthreads();
    }

    // epilogue: bias + tanh + per-class partial sums
    int l8[8];
    #pragma unroll
    for (int c8 = 0; c8 < 8; ++c8)
        l8[c8] = lab[(b << 14) + ((y0 + pg) << 7) + x0 + c8];
    float bv[8];
    #pragma unroll
    for (int cc = 0; cc < 8; ++cc) bv[cc] = bias[co0 + cog * 8 + cc];

    for (int e = t; e < S * 64; e += 256) part[e] = 0.f;
    __syncthreads();
    #pragma unroll
    for (int c8 = 0; c8 < 8; ++c8) {
        int sb = l8[c8] * 64 + cog * 8;
        #pragma unroll
        for (int cc = 0; cc < 8; ++cc)
            atomicAdd(&part[sb + cc], tanhf(acc[cc][c8] + bv[cc]));
    }
    __syncthreads();
    for (int e = t; e < S * 64; e += 256) {
        int s = e >> 6, col = e & 63;
        atomicAdd(&sumbuf[((b * S + s) << 9) + co0 + col], part[e]);
    }
}

// ---------------- finalize: divide by counts ----------------
__global__ LB void k_final(const float* __restrict__ sumbuf, const int* __restrict__ counts,
                           float* __restrict__ out) {
    int idx = blockIdx.x * 256 + threadIdx.x;   // 8*19*512
    int tt = idx >> 9;
    int s = tt % S, b = tt / S;
    int cnt = counts[b * S + s];
    out[idx] = cnt > 0 ? sumbuf[idx] / (float)cnt : 0.f;
}

extern "C" void kernel_launch(void* const* d_in, const int* in_sizes, int n_in,
                              void* d_out, int out_size, void* d_ws, size_t ws_size,
                              hipStream_t stream) {
    const float* input  = (const float*)d_in[0];
    const float* segmap = (const float*)d_in[1];
    const float* w1 = (const float*)d_in[2];  const float* b1 = (const float*)d_in[3];
    const float* w2 = (const float*)d_in[4];  const float* b2 = (const float*)d_in[5];
    const float* w3 = (const float*)d_in[6];  const float* b3 = (const float*)d_in[7];
    const float* w4 = (const float*)d_in[8];  const float* b4 = (const float*)d_in[9];
    const float* w5 = (const float*)d_in[10]; const float* b5 = (const float*)d_in[11];
    float* out = (float*)d_out;

    float* ws = (float*)d_ws;
    float* xA     = ws;                 // 33,554,432 floats: x1 then x4 (aliased)
    float* x2     = ws + 33554432;      // 8,388,608
    float* x3     = ws + 41943040;      // 4,194,304
    float* sumbuf = ws + 46137344;      // 77,824
    float* mean   = ws + 46215168;      // 2,048
    float* istd   = ws + 46217216;      // 2,048
    int*   lab    = (int*)(ws + 46219264);  // 131,072 ints
    int*   counts = (int*)(ws + 46350336);  // 256 ints

    hipMemsetAsync(sumbuf, 0, 77824 * sizeof(float), stream);
    hipMemsetAsync(counts, 0, 256 * sizeof(int), stream);

    // layer 1
    k_conv1<<<65536, 256, 0, stream>>>(input, w1, b1, xA);
    k_instats<<<256, 256, 0, stream>>>(xA, 65536, mean, istd);
    k_normlrelu<<<16384, 256, 0, stream>>>(xA, 65536, mean, istd);
    // layer 2
    k_conv_s2<32, 64, 256><<<32768, 256, 0, stream>>>(xA, w2, b2, x2);
    k_instats<<<512, 256, 0, stream>>>(x2, 16384, mean, istd);
    k_normlrelu<<<8192, 256, 0, stream>>>(x2, 16384, mean, istd);
    // layer 3
    k_conv_s2<64, 128, 128><<<16384, 256, 0, stream>>>(x2, w3, b3, x3);
    k_instats<<<1024, 256, 0, stream>>>(x3, 4096, mean, istd);
    k_normlrelu<<<4096, 256, 0, stream>>>(x3, 4096, mean, istd);
    // layer 4 (transpose conv) -> xA (x1 is dead)
    k_convt4<<<131072, 256, 0, stream>>>(x3, w4, b4, xA);
    k_instats<<<2048, 256, 0, stream>>>(xA, 16384, mean, istd);
    k_normlrelu<<<32768, 256, 0, stream>>>(xA, 16384, mean, istd);
    // label map + counts
    k_label<<<512, 256, 0, stream>>>(segmap, lab, counts);
    // layer 5 fused with masked class-sum
    k_conv5<<<4096, 256, 0, stream>>>(xA, w5, b5, lab, sumbuf);
    // finalize
    k_final<<<304, 256, 0, stream>>>(sumbuf, counts, out);
}

// Round 2
// 8004.904 us; speedup vs baseline: 1.8813x; 1.8813x over previous
//
#include <hip/hip_runtime.h>

#define LB __launch_bounds__(256)

constexpr int S = 19;

typedef __attribute__((ext_vector_type(8))) short frag16;   // 8 bf16 (4 VGPR)
typedef __attribute__((ext_vector_type(4))) float f32x4;

__device__ __forceinline__ int reflect256(int i) { return i < 0 ? -i : (i > 255 ? 510 - i : i); }

__device__ __forceinline__ ushort f2bf(float f) {
    union { float f; uint u; } a; a.f = f;
    uint r = a.u + 0x7fffu + ((a.u >> 16) & 1u);   // round-nearest-even
    return (ushort)(r >> 16);
}

// ---------------- conv1: [8,3,256,256] -> [8,32,256,256], reflect pad 1 ----------------
__global__ LB void k_conv1(const float* __restrict__ in, const float* __restrict__ w,
                           const float* __restrict__ bias, float* __restrict__ out) {
    int idx = blockIdx.x * 256 + threadIdx.x;
    int x = idx & 255, y = (idx >> 8) & 255, co = (idx >> 16) & 31, b = idx >> 21;
    float acc = bias[co];
    for (int ci = 0; ci < 3; ++ci) {
        const float* ip = in + ((b * 3 + ci) << 16);
        const float* wp = w + (co * 3 + ci) * 9;
        #pragma unroll
        for (int ky = 0; ky < 3; ++ky) {
            int iy = reflect256(y + ky - 1);
            #pragma unroll
            for (int kx = 0; kx < 3; ++kx) {
                int ix = reflect256(x + kx - 1);
                acc += ip[(iy << 8) + ix] * wp[ky * 3 + kx];
            }
        }
    }
    out[idx] = acc;
}

// ---------------- instance-norm stats: one block per (b,c) ----------------
__global__ LB void k_instats(const float* __restrict__ x, int HW,
                             float* __restrict__ mean, float* __restrict__ istd) {
    int bc = blockIdx.x;
    const float4* p = (const float4*)(x + (long)bc * HW);
    int n4 = HW >> 2;
    float s = 0.f, ss = 0.f;
    for (int i = threadIdx.x; i < n4; i += 256) {
        float4 v = p[i];
        s += v.x + v.y + v.z + v.w;
        ss += v.x * v.x + v.y * v.y + v.z * v.z + v.w * v.w;
    }
    #pragma unroll
    for (int o = 32; o > 0; o >>= 1) { s += __shfl_down(s, o); ss += __shfl_down(ss, o); }
    __shared__ float ls[4], lss[4];
    int wid = threadIdx.x >> 6;
    if ((threadIdx.x & 63) == 0) { ls[wid] = s; lss[wid] = ss; }
    __syncthreads();
    if (threadIdx.x == 0) {
        s = ls[0] + ls[1] + ls[2] + ls[3];
        ss = lss[0] + lss[1] + lss[2] + lss[3];
        float m = s / (float)HW;
        float v = ss / (float)HW - m * m;
        mean[bc] = m;
        istd[bc] = rsqrtf(v + 1e-5f);
    }
}

// ---------------- normalize + leaky-relu, in place, float4 (layers 1-3) ----------------
__global__ LB void k_normlrelu(float* __restrict__ x, int HW,
                               const float* __restrict__ mean, const float* __restrict__ istd) {
    long i = (long)blockIdx.x * 256 + threadIdx.x;   // index in float4 units
    int bc = (int)((i << 2) / HW);
    float m = mean[bc], is = istd[bc];
    float4* p = (float4*)x;
    float4 v = p[i];
    float t0 = (v.x - m) * is; v.x = t0 > 0.f ? t0 : 0.2f * t0;
    float t1 = (v.y - m) * is; v.y = t1 > 0.f ? t1 : 0.2f * t1;
    float t2 = (v.z - m) * is; v.z = t2 > 0.f ? t2 : 0.2f * t2;
    float t3 = (v.w - m) * is; v.w = t3 > 0.f ? t3 : 0.2f * t3;
    p[i] = v;
}

// ---------------- strided conv 3x3 s2 p1 (zero pad) ----------------
template <int CIN, int COUT, int HIN>
__global__ LB void k_conv_s2(const float* __restrict__ in, const float* __restrict__ w,
                             const float* __restrict__ bias, float* __restrict__ out) {
    constexpr int HOUT = HIN / 2;
    int idx = blockIdx.x * 256 + threadIdx.x;
    int x = idx % HOUT;
    int t = idx / HOUT;
    int y = t % HOUT; t /= HOUT;
    int co = t % COUT;
    int b = t / COUT;
    float acc = bias[co];
    const float* wbase = w + co * CIN * 9;
    #pragma unroll 4
    for (int ci = 0; ci < CIN; ++ci) {
        const float* ip = in + (long)(b * CIN + ci) * HIN * HIN;
        const float* wp = wbase + ci * 9;
        #pragma unroll
        for (int ky = 0; ky < 3; ++ky) {
            int iy = 2 * y + ky - 1;
            if (iy < 0 || iy >= HIN) continue;
            #pragma unroll
            for (int kx = 0; kx < 3; ++kx) {
                int ix = 2 * x + kx - 1;
                if (ix < 0 || ix >= HIN) continue;
                acc += ip[iy * HIN + ix] * wp[ky * 3 + kx];
            }
        }
    }
    out[idx] = acc;
}

// ---------------- conv-transpose: [8,128,64,64] -> [8,256,128,128], k3 s2 p1 op1 ----------------
__global__ LB void k_convt4(const float* __restrict__ in, const float* __restrict__ w,
                            const float* __restrict__ bias, float* __restrict__ out) {
    int idx = blockIdx.x * 256 + threadIdx.x;
    int x = idx & 127, y = (idx >> 7) & 127, co = (idx >> 14) & 255, b = idx >> 22;
    float acc = bias[co];
    #pragma unroll
    for (int ky = 0; ky < 3; ++ky) {
        int yy = y + 1 - ky;
        if (yy & 1) continue;
        int i = yy >> 1;
        if (i >= 64) continue;
        #pragma unroll
        for (int kx = 0; kx < 3; ++kx) {
            int xx = x + 1 - kx;
            if (xx & 1) continue;
            int j = xx >> 1;
            if (j >= 64) continue;
            const float* wp = w + (co * 3 + ky) * 3 + kx;
            const float* ip = in + ((b * 128) << 12) + (i << 6) + j;
            float a = 0.f;
            #pragma unroll 4
            for (int ci = 0; ci < 128; ++ci)
                a += ip[ci << 12] * wp[ci * 2304];
            acc += a;
        }
    }
    out[idx] = acc;
}

// ---------------- w5 transpose: [512][256][3][3] f32 -> [9][512][256] bf16 ----------------
__global__ LB void k_wt5(const float* __restrict__ w, ushort* __restrict__ wt) {
    int e = blockIdx.x * 256 + threadIdx.x;    // 1,179,648 total
    int ci = e & 255;
    int co = (e >> 8) & 511;
    int tap = e >> 17;
    wt[e] = f2bf(w[(co * 256 + ci) * 9 + tap]);
}

// ---------------- layer4 norm + lrelu + transpose to channels-last bf16 ----------------
// in: [8][256][128][128] f32 ; out: [8][128][128][256] bf16
__global__ LB void k_nlt4(const float* __restrict__ xr, const float* __restrict__ mean,
                          const float* __restrict__ istd, ushort* __restrict__ xl) {
    __shared__ __align__(16) ushort T[32 * 36];   // [x][c] pad 36
    int bx = blockIdx.x;
    int x0 = (bx & 3) * 32;
    int c0 = ((bx >> 2) & 7) * 32;
    int y  = (bx >> 5) & 127;
    int b  = bx >> 12;
    int t = threadIdx.x;
    {
        int c_l = t >> 3, xq = t & 7;
        int c = c0 + c_l;
        float m = mean[b * 256 + c], is = istd[b * 256 + c];
        float4 v = *(const float4*)(xr + (((long)(b * 256 + c)) << 14) + (y << 7) + x0 + xq * 4);
        float u;
        u = (v.x - m) * is; u = u > 0.f ? u : 0.2f * u; T[(xq * 4 + 0) * 36 + c_l] = f2bf(u);
        u = (v.y - m) * is; u = u > 0.f ? u : 0.2f * u; T[(xq * 4 + 1) * 36 + c_l] = f2bf(u);
        u = (v.z - m) * is; u = u > 0.f ? u : 0.2f * u; T[(xq * 4 + 2) * 36 + c_l] = f2bf(u);
        u = (v.w - m) * is; u = u > 0.f ? u : 0.2f * u; T[(xq * 4 + 3) * 36 + c_l] = f2bf(u);
    }
    __syncthreads();
    {
        int x_l = t >> 3, q = t & 7;
        ushort4 v = *(const ushort4*)&T[x_l * 36 + q * 4];
        long dst = ((((long)b << 14) + (y << 7) + x0 + x_l) << 8) + c0 + q * 4;
        *(ushort4*)&xl[dst] = v;
    }
}

// ---------------- label map @128x128 + per-class counts ----------------
__global__ LB void k_label(const float* __restrict__ segmap, int* __restrict__ lab,
                           int* __restrict__ counts) {
    __shared__ int h[S];
    if (threadIdx.x < S) h[threadIdx.x] = 0;
    __syncthreads();
    int idx = blockIdx.x * 256 + threadIdx.x;        // 8*128*128
    int x = idx & 127, y = (idx >> 7) & 127, b = idx >> 14;
    const float* sp = segmap + (long)b * S * 65536 + (y << 1) * 256 + (x << 1);
    int s = 0;
    for (int c = 0; c < S; ++c) {
        if (sp[c * 65536] > 0.f) { s = c; break; }
    }
    lab[idx] = s;
    atomicAdd(&h[s], 1);
    __syncthreads();
    if (threadIdx.x < S) atomicAdd(&counts[b * S + threadIdx.x], h[threadIdx.x]);
}

// ---------------- conv5 MFMA implicit GEMM + bias + tanh + masked class-sum ----------------
// xl: [8][128][128][256] bf16 channels-last; wt: [9][512][256] bf16
// block: b, co-tile 64, row-pair; 4 waves each 64co x 64pos; K = 32ci-chunks x 9 taps
__global__ LB void k_conv5m(const ushort* __restrict__ xl, const ushort* __restrict__ wt,
                            const float* __restrict__ bias, const int* __restrict__ lab,
                            float* __restrict__ sumbuf) {
    __shared__ __align__(16) ushort Xs[520 * 40];   // [4 rows][130 cols][40 ci-pad] 41.6KB
    __shared__ float part[S * 64];

    int bx = blockIdx.x;
    int yp = bx & 63;
    int ct = (bx >> 6) & 7;
    int b  = bx >> 9;
    int y0 = yp * 2, co0 = ct * 64;
    int t = threadIdx.x;
    int w = t >> 6;
    int lane = t & 63;
    int row_w = w >> 1;            // 0 or 1
    int col0 = (w & 1) * 64;
    int lanep = lane & 15;
    int laneq = (lane >> 4) * 8;   // ci sub-offset
    int hi = lane >> 4;

    f32x4 acc[4][4];
    #pragma unroll
    for (int m = 0; m < 4; ++m)
        #pragma unroll
        for (int n = 0; n < 4; ++n) acc[m][n] = (f32x4){0.f, 0.f, 0.f, 0.f};

    for (int ci0 = 0; ci0 < 256; ci0 += 32) {
        // stage 4 rows x 130 cols x 32 ci (bf16, reflect pad)
        for (int e = t; e < 2080; e += 256) {
            int p = e >> 2, q = e & 3;
            int r = p / 130, x = p - r * 130;
            int gy = y0 - 1 + r; gy = gy < 0 ? -gy : (gy > 127 ? 254 - gy : gy);
            int gx = x - 1;      gx = gx < 0 ? -gx : (gx > 127 ? 254 - gx : gx);
            frag16 v = *(const frag16*)(xl + ((((long)b << 14) + (gy << 7) + gx) << 8) + ci0 + q * 8);
            *(frag16*)(Xs + p * 40 + q * 8) = v;
        }
        __syncthreads();

        frag16 a_cur[4], a_nxt[4];
        #pragma unroll
        for (int m = 0; m < 4; ++m)
            a_cur[m] = *(const frag16*)(wt + (co0 + m * 16 + lanep) * 256 + ci0 + laneq);

        #pragma unroll
        for (int tap = 0; tap < 9; ++tap) {
            int ky = tap / 3, kx = tap % 3;
            if (tap < 8) {
                #pragma unroll
                for (int m = 0; m < 4; ++m)
                    a_nxt[m] = *(const frag16*)(wt + ((tap + 1) * 512 + co0 + m * 16 + lanep) * 256 + ci0 + laneq);
            }
            frag16 bfr[4];
            int rbase = ((row_w + ky) * 130 + col0 + kx + lanep) * 40 + laneq;
            #pragma unroll
            for (int n = 0; n < 4; ++n)
                bfr[n] = *(const frag16*)(Xs + rbase + n * (16 * 40));
            #pragma unroll
            for (int m = 0; m < 4; ++m)
                #pragma unroll
                for (int n = 0; n < 4; ++n)
                    acc[m][n] = __builtin_amdgcn_mfma_f32_16x16x32_bf16(a_cur[m], bfr[n], acc[m][n], 0, 0, 0);
            #pragma unroll
            for (int m = 0; m < 4; ++m) a_cur[m] = a_nxt[m];
        }
        __syncthreads();
    }

    // epilogue: bias + tanh + per-class partial sums
    float bv[4][4];
    #pragma unroll
    for (int m = 0; m < 4; ++m)
        #pragma unroll
        for (int r = 0; r < 4; ++r)
            bv[m][r] = bias[co0 + m * 16 + hi * 4 + r];

    for (int e = t; e < S * 64; e += 256) part[e] = 0.f;
    __syncthreads();

    int y = y0 + row_w;
    #pragma unroll
    for (int n = 0; n < 4; ++n) {
        int x = col0 + n * 16 + lanep;
        int s = lab[(b << 14) + (y << 7) + x];
        #pragma unroll
        for (int m = 0; m < 4; ++m)
            #pragma unroll
            for (int r = 0; r < 4; ++r)
                atomicAdd(&part[s * 64 + m * 16 + hi * 4 + r], tanhf(acc[m][n][r] + bv[m][r]));
    }
    __syncthreads();
    for (int e = t; e < S * 64; e += 256) {
        int s = e >> 6, col = e & 63;
        atomicAdd(&sumbuf[((b * S + s) << 9) + co0 + col], part[e]);
    }
}

// ---------------- finalize: divide by counts ----------------
__global__ LB void k_final(const float* __restrict__ sumbuf, const int* __restrict__ counts,
                           float* __restrict__ out) {
    int idx = blockIdx.x * 256 + threadIdx.x;   // 8*19*512
    int tt = idx >> 9;
    int s = tt % S, b = tt / S;
    int cnt = counts[b * S + s];
    out[idx] = cnt > 0 ? sumbuf[idx] / (float)cnt : 0.f;
}

extern "C" void kernel_launch(void* const* d_in, const int* in_sizes, int n_in,
                              void* d_out, int out_size, void* d_ws, size_t ws_size,
                              hipStream_t stream) {
    const float* input  = (const float*)d_in[0];
    const float* segmap = (const float*)d_in[1];
    const float* w1 = (const float*)d_in[2];  const float* b1 = (const float*)d_in[3];
    const float* w2 = (const float*)d_in[4];  const float* b2 = (const float*)d_in[5];
    const float* w3 = (const float*)d_in[6];  const float* b3 = (const float*)d_in[7];
    const float* w4 = (const float*)d_in[8];  const float* b4 = (const float*)d_in[9];
    const float* w5 = (const float*)d_in[10]; const float* b5 = (const float*)d_in[11];
    float* out = (float*)d_out;

    float* ws = (float*)d_ws;
    // Region A [0, 33554432): x1 (16.7M) then x4raw (33.5M, overwrites dead x1)
    float* x1     = ws;
    float* x4raw  = ws;
    // Region B [33554432, 50331648): x2, x3; later xl (bf16 channels-last, 67MB exact)
    float* x2     = ws + 33554432;
    float* x3     = ws + 41943040;
    ushort* xl    = (ushort*)(ws + 33554432);
    // misc
    float* sumbuf = ws + 50331648;              // 77,824
    float* mean   = ws + 50409472;              // 2,048
    float* istd   = ws + 50411520;              // 2,048
    int*   lab    = (int*)(ws + 50413568);      // 131,072 ints
    int*   counts = (int*)(ws + 50544640);      // 256 ints
    ushort* wt5   = (ushort*)(ws + 50544896);   // 1,179,648 bf16

    hipMemsetAsync(sumbuf, 0, 77824 * sizeof(float), stream);
    hipMemsetAsync(counts, 0, 256 * sizeof(int), stream);

    k_wt5<<<4608, 256, 0, stream>>>(w5, wt5);
    // layer 1
    k_conv1<<<65536, 256, 0, stream>>>(input, w1, b1, x1);
    k_instats<<<256, 256, 0, stream>>>(x1, 65536, mean, istd);
    k_normlrelu<<<16384, 256, 0, stream>>>(x1, 65536, mean, istd);
    // layer 2
    k_conv_s2<32, 64, 256><<<32768, 256, 0, stream>>>(x1, w2, b2, x2);
    k_instats<<<512, 256, 0, stream>>>(x2, 16384, mean, istd);
    k_normlrelu<<<8192, 256, 0, stream>>>(x2, 16384, mean, istd);
    // layer 3
    k_conv_s2<64, 128, 128><<<16384, 256, 0, stream>>>(x2, w3, b3, x3);
    k_instats<<<1024, 256, 0, stream>>>(x3, 4096, mean, istd);
    k_normlrelu<<<4096, 256, 0, stream>>>(x3, 4096, mean, istd);
    // layer 4 (transpose conv) -> x4raw (x1 dead)
    k_convt4<<<131072, 256, 0, stream>>>(x3, w4, b4, x4raw);
    k_instats<<<2048, 256, 0, stream>>>(x4raw, 16384, mean, istd);
    k_nlt4<<<32768, 256, 0, stream>>>(x4raw, mean, istd, xl);   // overwrites dead x2/x3
    // label map + counts
    k_label<<<512, 256, 0, stream>>>(segmap, lab, counts);
    // layer 5: MFMA implicit GEMM fused with masked class-sum
    k_conv5m<<<4096, 256, 0, stream>>>(xl, wt5, b5, lab, sumbuf);
    // finalize
    k_final<<<304, 256, 0, stream>>>(sumbuf, counts, out);
}

// Round 3
// 3928.087 us; speedup vs baseline: 3.8338x; 2.0379x over previous
//
#include <hip/hip_runtime.h>

#define LB __launch_bounds__(256)

constexpr int S = 19;

typedef __attribute__((ext_vector_type(8))) short frag16;   // 8 bf16 (4 VGPR)
typedef __attribute__((ext_vector_type(8))) ushort ushort8;
typedef __attribute__((ext_vector_type(4))) float f32x4;

__device__ __forceinline__ int reflect256(int i) { return i < 0 ? -i : (i > 255 ? 510 - i : i); }

__device__ __forceinline__ ushort f2bf(float f) {
    union { float f; uint u; } a; a.f = f;
    uint r = a.u + 0x7fffu + ((a.u >> 16) & 1u);   // round-nearest-even
    return (ushort)(r >> 16);
}
__device__ __forceinline__ float bf2f(ushort u) {
    union { uint u; float f; } a; a.u = ((uint)u) << 16; return a.f;
}

// ---------------- conv1: [8,3,256,256] -> [8,32,256,256], reflect pad 1 ----------------
__global__ LB void k_conv1(const float* __restrict__ in, const float* __restrict__ w,
                           const float* __restrict__ bias, float* __restrict__ out) {
    int idx = blockIdx.x * 256 + threadIdx.x;
    int x = idx & 255, y = (idx >> 8) & 255, co = (idx >> 16) & 31, b = idx >> 21;
    float acc = bias[co];
    for (int ci = 0; ci < 3; ++ci) {
        const float* ip = in + ((b * 3 + ci) << 16);
        const float* wp = w + (co * 3 + ci) * 9;
        #pragma unroll
        for (int ky = 0; ky < 3; ++ky) {
            int iy = reflect256(y + ky - 1);
            #pragma unroll
            for (int kx = 0; kx < 3; ++kx) {
                int ix = reflect256(x + kx - 1);
                acc += ip[(iy << 8) + ix] * wp[ky * 3 + kx];
            }
        }
    }
    out[idx] = acc;
}

// ---------------- instance-norm stats (NCHW): one block per (b,c) ----------------
__global__ LB void k_instats(const float* __restrict__ x, int HW,
                             float* __restrict__ mean, float* __restrict__ istd) {
    int bc = blockIdx.x;
    const float4* p = (const float4*)(x + (long)bc * HW);
    int n4 = HW >> 2;
    float s = 0.f, ss = 0.f;
    for (int i = threadIdx.x; i < n4; i += 256) {
        float4 v = p[i];
        s += v.x + v.y + v.z + v.w;
        ss += v.x * v.x + v.y * v.y + v.z * v.z + v.w * v.w;
    }
    #pragma unroll
    for (int o = 32; o > 0; o >>= 1) { s += __shfl_down(s, o); ss += __shfl_down(ss, o); }
    __shared__ float ls[4], lss[4];
    int wid = threadIdx.x >> 6;
    if ((threadIdx.x & 63) == 0) { ls[wid] = s; lss[wid] = ss; }
    __syncthreads();
    if (threadIdx.x == 0) {
        s = ls[0] + ls[1] + ls[2] + ls[3];
        ss = lss[0] + lss[1] + lss[2] + lss[3];
        float m = s / (float)HW;
        float v = ss / (float)HW - m * m;
        mean[bc] = m;
        istd[bc] = rsqrtf(v + 1e-5f);
    }
}

// ---------------- normalize + leaky-relu, in place, float4 (layers 1-2) ----------------
__global__ LB void k_normlrelu(float* __restrict__ x, int HW,
                               const float* __restrict__ mean, const float* __restrict__ istd) {
    long i = (long)blockIdx.x * 256 + threadIdx.x;   // index in float4 units
    int bc = (int)((i << 2) / HW);
    float m = mean[bc], is = istd[bc];
    float4* p = (float4*)x;
    float4 v = p[i];
    float t0 = (v.x - m) * is; v.x = t0 > 0.f ? t0 : 0.2f * t0;
    float t1 = (v.y - m) * is; v.y = t1 > 0.f ? t1 : 0.2f * t1;
    float t2 = (v.z - m) * is; v.z = t2 > 0.f ? t2 : 0.2f * t2;
    float t3 = (v.w - m) * is; v.w = t3 > 0.f ? t3 : 0.2f * t3;
    p[i] = v;
}

// ---------------- strided conv 3x3 s2 p1 (zero pad) ----------------
template <int CIN, int COUT, int HIN>
__global__ LB void k_conv_s2(const float* __restrict__ in, const float* __restrict__ w,
                             const float* __restrict__ bias, float* __restrict__ out) {
    constexpr int HOUT = HIN / 2;
    int idx = blockIdx.x * 256 + threadIdx.x;
    int x = idx % HOUT;
    int t = idx / HOUT;
    int y = t % HOUT; t /= HOUT;
    int co = t % COUT;
    int b = t / COUT;
    float acc = bias[co];
    const float* wbase = w + co * CIN * 9;
    #pragma unroll 4
    for (int ci = 0; ci < CIN; ++ci) {
        const float* ip = in + (long)(b * CIN + ci) * HIN * HIN;
        const float* wp = wbase + ci * 9;
        #pragma unroll
        for (int ky = 0; ky < 3; ++ky) {
            int iy = 2 * y + ky - 1;
            if (iy < 0 || iy >= HIN) continue;
            #pragma unroll
            for (int kx = 0; kx < 3; ++kx) {
                int ix = 2 * x + kx - 1;
                if (ix < 0 || ix >= HIN) continue;
                acc += ip[iy * HIN + ix] * wp[ky * 3 + kx];
            }
        }
    }
    out[idx] = acc;
}

// ---------------- layer3 norm + lrelu + transpose to channels-last bf16 ----------------
// in: [8][128][64][64] f32 (raw conv out) ; out: [8][64][64][128] bf16
__global__ LB void k_nlt3(const float* __restrict__ xr, const float* __restrict__ mean,
                          const float* __restrict__ istd, ushort* __restrict__ xl) {
    __shared__ __align__(16) ushort T[32 * 36];   // [x][c] pad 36
    int bx = blockIdx.x;
    int x0 = (bx & 1) * 32;
    int c0 = ((bx >> 1) & 3) * 32;
    int y  = (bx >> 3) & 63;
    int b  = bx >> 9;
    int t = threadIdx.x;
    {
        int c_l = t >> 3, xq = t & 7;
        int c = c0 + c_l;
        float m = mean[b * 128 + c], is = istd[b * 128 + c];
        float4 v = *(const float4*)(xr + (((long)(b * 128 + c)) << 12) + (y << 6) + x0 + xq * 4);
        float u;
        u = (v.x - m) * is; u = u > 0.f ? u : 0.2f * u; T[(xq * 4 + 0) * 36 + c_l] = f2bf(u);
        u = (v.y - m) * is; u = u > 0.f ? u : 0.2f * u; T[(xq * 4 + 1) * 36 + c_l] = f2bf(u);
        u = (v.z - m) * is; u = u > 0.f ? u : 0.2f * u; T[(xq * 4 + 2) * 36 + c_l] = f2bf(u);
        u = (v.w - m) * is; u = u > 0.f ? u : 0.2f * u; T[(xq * 4 + 3) * 36 + c_l] = f2bf(u);
    }
    __syncthreads();
    {
        int x_l = t >> 3, q = t & 7;
        ushort4 v = *(const ushort4*)&T[x_l * 36 + q * 4];
        long dst = ((((long)b << 12) + (y << 6) + x0 + x_l) << 7) + c0 + q * 4;
        *(ushort4*)&xl[dst] = v;
    }
}

// ---------------- w5 transpose: [512][256][3][3] f32 -> [9][512][256] bf16 ----------------
__global__ LB void k_wt5(const float* __restrict__ w, ushort* __restrict__ wt) {
    int e = blockIdx.x * 256 + threadIdx.x;    // 1,179,648 total
    int ci = e & 255;
    int co = (e >> 8) & 511;
    int tap = e >> 17;
    wt[e] = f2bf(w[(co * 256 + ci) * 9 + tap]);
}

// ---------------- w4 transpose: [128][256][3][3] f32 (Cin,Cout,kh,kw) -> [9][256][128] bf16 ----------------
__global__ LB void k_wt4(const float* __restrict__ w, ushort* __restrict__ wt) {
    int e = blockIdx.x * 256 + threadIdx.x;    // 294,912 total
    int ci = e & 127;
    int co = (e >> 7) & 255;
    int tap = e >> 15;
    wt[e] = f2bf(w[ci * 2304 + co * 9 + tap]);
}

// ---------------- convT4 MFMA implicit GEMM (parity decomposition), bias, bf16 CL out ----
// x3l: [8][64][64][128] bf16; wt: [9][256][128] bf16; out xl: [8][128][128][256] bf16
// block: parity(py,px), b, co-tile 64, rowgroup of 4 output rows; 4 waves = 4 rows, each 64co x 64pos
__global__ LB void k_convt4m(const ushort* __restrict__ x3l, const ushort* __restrict__ wt,
                             const float* __restrict__ bias, ushort* __restrict__ xl) {
    int bx = blockIdx.x;
    int parity = bx & 3;
    int py = parity >> 1, px = parity & 1;
    int rg = (bx >> 2) & 15;
    int ct = (bx >> 6) & 3;
    int b  = bx >> 8;
    int co0 = ct * 64;
    int t = threadIdx.x;
    int w = t >> 6;
    int ip = rg * 4 + w;           // i' (output row index within parity class)
    int lane = t & 63;
    int lanep = lane & 15;
    int hi = lane >> 4;
    int laneq = hi * 8;

    f32x4 acc[4][4];
    #pragma unroll
    for (int m = 0; m < 4; ++m)
        #pragma unroll
        for (int n = 0; n < 4; ++n) acc[m][n] = (f32x4){0.f, 0.f, 0.f, 0.f};

    #pragma unroll
    for (int ky = 0; ky < 3; ++ky) {
        if (((ky + py) & 1) == 0) continue;         // tap inactive for this row parity
        int i = ip + ((py == 1 && ky == 0) ? 1 : 0);
        if (i >= 64) continue;                       // wave-uniform skip
        #pragma unroll
        for (int kx = 0; kx < 3; ++kx) {
            if (((kx + px) & 1) == 0) continue;
            int dxp = (px == 1 && kx == 0) ? 1 : 0;
            int tap = ky * 3 + kx;
            const ushort* wbase = wt + (((long)tap * 256 + co0 + lanep) << 7) + laneq;
            const ushort* xbase = x3l + ((((long)b << 12) + (i << 6)) << 7) + laneq;
            #pragma unroll
            for (int ci0 = 0; ci0 < 128; ci0 += 32) {
                frag16 av[4], bv[4];
                #pragma unroll
                for (int m = 0; m < 4; ++m)
                    av[m] = *(const frag16*)(wbase + ((m * 16) << 7) + ci0);
                #pragma unroll
                for (int n = 0; n < 4; ++n) {
                    int j = n * 16 + lanep + dxp;
                    bool valid = j < 64;
                    frag16 v = *(const frag16*)(xbase + ((valid ? j : 63) << 7) + ci0);
                    if (!valid) v = (frag16)(short)0;
                    bv[n] = v;
                }
                #pragma unroll
                for (int m = 0; m < 4; ++m)
                    #pragma unroll
                    for (int n = 0; n < 4; ++n)
                        acc[m][n] = __builtin_amdgcn_mfma_f32_16x16x32_bf16(av[m], bv[n], acc[m][n], 0, 0, 0);
            }
        }
    }

    // epilogue: bias, cvt bf16, store channels-last
    float bvv[4][4];
    #pragma unroll
    for (int m = 0; m < 4; ++m)
        #pragma unroll
        for (int r = 0; r < 4; ++r)
            bvv[m][r] = bias[co0 + m * 16 + hi * 4 + r];
    int y = 2 * ip + py;
    #pragma unroll
    for (int n = 0; n < 4; ++n) {
        int x = 2 * (n * 16 + lanep) + px;
        long pb = ((((long)b << 14) + (y << 7) + x) << 8) + co0 + hi * 4;
        #pragma unroll
        for (int m = 0; m < 4; ++m) {
            ushort4 o;
            o.x = f2bf(acc[m][n][0] + bvv[m][0]);
            o.y = f2bf(acc[m][n][1] + bvv[m][1]);
            o.z = f2bf(acc[m][n][2] + bvv[m][2]);
            o.w = f2bf(acc[m][n][3] + bvv[m][3]);
            *(ushort4*)(xl + pb + m * 16) = o;
        }
    }
}

// ---------------- instance-norm stats, channels-last bf16: partial sums ----------------
// xl: [8][16384][256] bf16 ; psum/pss: [8*32][256]
__global__ LB void k_instats_cl(const ushort* __restrict__ xl,
                                float* __restrict__ psum, float* __restrict__ pss) {
    __shared__ float lsum[256], lss[256];
    int b = blockIdx.x >> 5, split = blockIdx.x & 31;
    int t = threadIdx.x;
    lsum[t] = 0.f; lss[t] = 0.f;
    __syncthreads();
    int c0 = (t & 31) * 8;
    int po = t >> 5;               // 0..7
    float s[8], ss[8];
    #pragma unroll
    for (int k = 0; k < 8; ++k) { s[k] = 0.f; ss[k] = 0.f; }
    const ushort* base = xl + ((long)b << 22) + (long)split * 512 * 256;
    for (int p = po; p < 512; p += 8) {
        ushort8 v = *(const ushort8*)(base + p * 256 + c0);
        #pragma unroll
        for (int k = 0; k < 8; ++k) {
            float f = bf2f(v[k]);
            s[k] += f; ss[k] += f * f;
        }
    }
    #pragma unroll
    for (int k = 0; k < 8; ++k) {
        atomicAdd(&lsum[c0 + k], s[k]);
        atomicAdd(&lss[c0 + k], ss[k]);
    }
    __syncthreads();
    psum[blockIdx.x * 256 + t] = lsum[t];
    pss[blockIdx.x * 256 + t] = lss[t];
}

// ---------------- reduce partials -> mean/istd ----------------
__global__ LB void k_redcl(const float* __restrict__ psum, const float* __restrict__ pss,
                           float* __restrict__ mean, float* __restrict__ istd) {
    int b = blockIdx.x, c = threadIdx.x;
    float s = 0.f, ss = 0.f;
    for (int sp = 0; sp < 32; ++sp) {
        s += psum[(b * 32 + sp) * 256 + c];
        ss += pss[(b * 32 + sp) * 256 + c];
    }
    float m = s / 16384.f;
    float v = ss / 16384.f - m * m;
    mean[b * 256 + c] = m;
    istd[b * 256 + c] = rsqrtf(v + 1e-5f);
}

// ---------------- layer4 norm + lrelu, in place on channels-last bf16 ----------------
__global__ LB void k_nl4cl(ushort* __restrict__ xl, const float* __restrict__ mean,
                           const float* __restrict__ istd) {
    long e = ((long)blockIdx.x * 256 + threadIdx.x) * 8;
    int c0 = (int)(e & 255);
    int b = (int)(e >> 22);
    ushort8 v = *(ushort8*)(xl + e);
    const float* mp = mean + b * 256 + c0;
    const float* ip = istd + b * 256 + c0;
    float4 m0 = *(const float4*)mp, m1 = *(const float4*)(mp + 4);
    float4 i0 = *(const float4*)ip, i1 = *(const float4*)(ip + 4);
    float mm[8] = {m0.x, m0.y, m0.z, m0.w, m1.x, m1.y, m1.z, m1.w};
    float ii[8] = {i0.x, i0.y, i0.z, i0.w, i1.x, i1.y, i1.z, i1.w};
    #pragma unroll
    for (int k = 0; k < 8; ++k) {
        float u = (bf2f(v[k]) - mm[k]) * ii[k];
        u = u > 0.f ? u : 0.2f * u;
        v[k] = f2bf(u);
    }
    *(ushort8*)(xl + e) = v;
}

// ---------------- label map @128x128 + per-class counts ----------------
__global__ LB void k_label(const float* __restrict__ segmap, int* __restrict__ lab,
                           int* __restrict__ counts) {
    __shared__ int h[S];
    if (threadIdx.x < S) h[threadIdx.x] = 0;
    __syncthreads();
    int idx = blockIdx.x * 256 + threadIdx.x;        // 8*128*128
    int x = idx & 127, y = (idx >> 7) & 127, b = idx >> 14;
    const float* sp = segmap + (long)b * S * 65536 + (y << 1) * 256 + (x << 1);
    int s = 0;
    for (int c = 0; c < S; ++c) {
        if (sp[c * 65536] > 0.f) { s = c; break; }
    }
    lab[idx] = s;
    atomicAdd(&h[s], 1);
    __syncthreads();
    if (threadIdx.x < S) atomicAdd(&counts[b * S + threadIdx.x], h[threadIdx.x]);
}

// ---------------- conv5 MFMA implicit GEMM + bias + tanh + masked class-sum ----------------
__global__ LB void k_conv5m(const ushort* __restrict__ xl, const ushort* __restrict__ wt,
                            const float* __restrict__ bias, const int* __restrict__ lab,
                            float* __restrict__ sumbuf) {
    __shared__ __align__(16) ushort Xs[520 * 40];   // [4 rows][130 cols][40 ci-pad]
    __shared__ float part[S * 64];

    int bx = blockIdx.x;
    int yp = bx & 63;
    int ct = (bx >> 6) & 7;
    int b  = bx >> 9;
    int y0 = yp * 2, co0 = ct * 64;
    int t = threadIdx.x;
    int w = t >> 6;
    int lane = t & 63;
    int row_w = w >> 1;            // 0 or 1
    int col0 = (w & 1) * 64;
    int lanep = lane & 15;
    int laneq = (lane >> 4) * 8;   // ci sub-offset
    int hi = lane >> 4;

    f32x4 acc[4][4];
    #pragma unroll
    for (int m = 0; m < 4; ++m)
        #pragma unroll
        for (int n = 0; n < 4; ++n) acc[m][n] = (f32x4){0.f, 0.f, 0.f, 0.f};

    for (int ci0 = 0; ci0 < 256; ci0 += 32) {
        for (int e = t; e < 2080; e += 256) {
            int p = e >> 2, q = e & 3;
            int r = p / 130, x = p - r * 130;
            int gy = y0 - 1 + r; gy = gy < 0 ? -gy : (gy > 127 ? 254 - gy : gy);
            int gx = x - 1;      gx = gx < 0 ? -gx : (gx > 127 ? 254 - gx : gx);
            frag16 v = *(const frag16*)(xl + ((((long)b << 14) + (gy << 7) + gx) << 8) + ci0 + q * 8);
            *(frag16*)(Xs + p * 40 + q * 8) = v;
        }
        __syncthreads();

        frag16 a_cur[4], a_nxt[4];
        #pragma unroll
        for (int m = 0; m < 4; ++m)
            a_cur[m] = *(const frag16*)(wt + (co0 + m * 16 + lanep) * 256 + ci0 + laneq);

        #pragma unroll
        for (int tap = 0; tap < 9; ++tap) {
            int ky = tap / 3, kx = tap % 3;
            if (tap < 8) {
                #pragma unroll
                for (int m = 0; m < 4; ++m)
                    a_nxt[m] = *(const frag16*)(wt + ((tap + 1) * 512 + co0 + m * 16 + lanep) * 256 + ci0 + laneq);
            }
            frag16 bfr[4];
            int rbase = ((row_w + ky) * 130 + col0 + kx + lanep) * 40 + laneq;
            #pragma unroll
            for (int n = 0; n < 4; ++n)
                bfr[n] = *(const frag16*)(Xs + rbase + n * (16 * 40));
            #pragma unroll
            for (int m = 0; m < 4; ++m)
                #pragma unroll
                for (int n = 0; n < 4; ++n)
                    acc[m][n] = __builtin_amdgcn_mfma_f32_16x16x32_bf16(a_cur[m], bfr[n], acc[m][n], 0, 0, 0);
            #pragma unroll
            for (int m = 0; m < 4; ++m) a_cur[m] = a_nxt[m];
        }
        __syncthreads();
    }

    float bv[4][4];
    #pragma unroll
    for (int m = 0; m < 4; ++m)
        #pragma unroll
        for (int r = 0; r < 4; ++r)
            bv[m][r] = bias[co0 + m * 16 + hi * 4 + r];

    for (int e = t; e < S * 64; e += 256) part[e] = 0.f;
    __syncthreads();

    int y = y0 + row_w;
    #pragma unroll
    for (int n = 0; n < 4; ++n) {
        int x = col0 + n * 16 + lanep;
        int s = lab[(b << 14) + (y << 7) + x];
        #pragma unroll
        for (int m = 0; m < 4; ++m)
            #pragma unroll
            for (int r = 0; r < 4; ++r)
                atomicAdd(&part[s * 64 + m * 16 + hi * 4 + r], tanhf(acc[m][n][r] + bv[m][r]));
    }
    __syncthreads();
    for (int e = t; e < S * 64; e += 256) {
        int s = e >> 6, col = e & 63;
        atomicAdd(&sumbuf[((b * S + s) << 9) + co0 + col], part[e]);
    }
}

// ---------------- finalize: divide by counts ----------------
__global__ LB void k_final(const float* __restrict__ sumbuf, const int* __restrict__ counts,
                           float* __restrict__ out) {
    int idx = blockIdx.x * 256 + threadIdx.x;   // 8*19*512
    int tt = idx >> 9;
    int s = tt % S, b = tt / S;
    int cnt = counts[b * S + s];
    out[idx] = cnt > 0 ? sumbuf[idx] / (float)cnt : 0.f;
}

extern "C" void kernel_launch(void* const* d_in, const int* in_sizes, int n_in,
                              void* d_out, int out_size, void* d_ws, size_t ws_size,
                              hipStream_t stream) {
    const float* input  = (const float*)d_in[0];
    const float* segmap = (const float*)d_in[1];
    const float* w1 = (const float*)d_in[2];  const float* b1 = (const float*)d_in[3];
    const float* w2 = (const float*)d_in[4];  const float* b2 = (const float*)d_in[5];
    const float* w3 = (const float*)d_in[6];  const float* b3 = (const float*)d_in[7];
    const float* w4 = (const float*)d_in[8];  const float* b4 = (const float*)d_in[9];
    const float* w5 = (const float*)d_in[10]; const float* b5 = (const float*)d_in[11];
    float* out = (float*)d_out;

    float* ws = (float*)d_ws;
    // region [0, 16777216): x1 (f32, conv1 out) -> later xl (bf16 channels-last, 67MB)
    float*  x1   = ws;
    ushort* xl   = (ushort*)ws;
    float*  x2   = ws + 16777216;               // 8,388,608 f32
    float*  x3   = ws + 25165824;               // 4,194,304 f32
    ushort* x3l  = (ushort*)(ws + 29360128);    // 4,194,304 bf16 (2,097,152 f32 slots)
    float* sumbuf = ws + 31457280;              // 77,824
    float* mean   = ws + 31535104;              // 2,048
    float* istd   = ws + 31537152;              // 2,048
    int*   lab    = (int*)(ws + 31539200);      // 131,072 ints
    int*   counts = (int*)(ws + 31670272);      // 256 ints
    ushort* wt5   = (ushort*)(ws + 31670528);   // 1,179,648 bf16
    ushort* wt4t  = (ushort*)(ws + 32260352);   // 294,912 bf16
    float* psum   = ws + 32407808;              // 65,536
    float* pss    = ws + 32473344;              // 65,536

    hipMemsetAsync(sumbuf, 0, 77824 * sizeof(float), stream);
    hipMemsetAsync(counts, 0, 256 * sizeof(int), stream);

    k_wt5<<<4608, 256, 0, stream>>>(w5, wt5);
    k_wt4<<<1152, 256, 0, stream>>>(w4, wt4t);
    // layer 1
    k_conv1<<<65536, 256, 0, stream>>>(input, w1, b1, x1);
    k_instats<<<256, 256, 0, stream>>>(x1, 65536, mean, istd);
    k_normlrelu<<<16384, 256, 0, stream>>>(x1, 65536, mean, istd);
    // layer 2
    k_conv_s2<32, 64, 256><<<32768, 256, 0, stream>>>(x1, w2, b2, x2);
    k_instats<<<512, 256, 0, stream>>>(x2, 16384, mean, istd);
    k_normlrelu<<<8192, 256, 0, stream>>>(x2, 16384, mean, istd);
    // layer 3 (norm fused with channels-last bf16 transpose)
    k_conv_s2<64, 128, 128><<<16384, 256, 0, stream>>>(x2, w3, b3, x3);
    k_instats<<<1024, 256, 0, stream>>>(x3, 4096, mean, istd);
    k_nlt3<<<4096, 256, 0, stream>>>(x3, mean, istd, x3l);
    // layer 4: MFMA transpose-conv -> bf16 channels-last (overwrites dead x1)
    k_convt4m<<<2048, 256, 0, stream>>>(x3l, wt4t, b4, xl);
    k_instats_cl<<<256, 256, 0, stream>>>(xl, psum, pss);
    k_redcl<<<8, 256, 0, stream>>>(psum, pss, mean, istd);
    k_nl4cl<<<16384, 256, 0, stream>>>(xl, mean, istd);
    // label map + counts
    k_label<<<512, 256, 0, stream>>>(segmap, lab, counts);
    // layer 5: MFMA implicit GEMM fused with masked class-sum
    k_conv5m<<<4096, 256, 0, stream>>>(xl, wt5, b5, lab, sumbuf);
    // finalize
    k_final<<<304, 256, 0, stream>>>(sumbuf, counts, out);
}

// Round 4
// 1336.955 us; speedup vs baseline: 11.2641x; 2.9381x over previous
//
#include <hip/hip_runtime.h>

#define LB __launch_bounds__(256)

constexpr int S = 19;

typedef __attribute__((ext_vector_type(8))) short frag16;   // 8 bf16 (4 VGPR)
typedef __attribute__((ext_vector_type(8))) ushort ushort8;
typedef __attribute__((ext_vector_type(4))) float f32x4;

__device__ __forceinline__ int reflect256(int i) { return i < 0 ? -i : (i > 255 ? 510 - i : i); }

__device__ __forceinline__ ushort f2bf(float f) {
    union { float f; uint u; } a; a.f = f;
    uint r = a.u + 0x7fffu + ((a.u >> 16) & 1u);   // round-nearest-even
    return (ushort)(r >> 16);
}
__device__ __forceinline__ float bf2f(ushort u) {
    union { uint u; float f; } a; a.u = ((uint)u) << 16; return a.f;
}

// ---------------- conv1: [8,3,256,256] f32 -> [8,256,256,32] bf16 CL, reflect pad ----------------
__global__ LB void k_conv1cl(const float* __restrict__ in, const float* __restrict__ w,
                             const float* __restrict__ bias, ushort* __restrict__ out) {
    __shared__ float Wr[864];   // [co][ci*9+tap]
    __shared__ float Bs[32];
    int t = threadIdx.x;
    for (int e = t; e < 864; e += 256) Wr[e] = w[e];
    if (t < 32) Bs[t] = bias[t];
    __syncthreads();
    int idx = blockIdx.x * 256 + t;          // 524288 pixels
    int x = idx & 255, y = (idx >> 8) & 255, b = idx >> 16;
    float v[27];
    #pragma unroll
    for (int ci = 0; ci < 3; ++ci) {
        const float* ip = in + ((b * 3 + ci) << 16);
        #pragma unroll
        for (int ky = 0; ky < 3; ++ky) {
            int iy = reflect256(y + ky - 1);
            #pragma unroll
            for (int kx = 0; kx < 3; ++kx) {
                int ix = reflect256(x + kx - 1);
                v[ci * 9 + ky * 3 + kx] = ip[(iy << 8) + ix];
            }
        }
    }
    ushort* op = out + (long)idx * 32;
    #pragma unroll
    for (int g = 0; g < 4; ++g) {
        ushort8 o;
        #pragma unroll
        for (int j = 0; j < 8; ++j) {
            int co = g * 8 + j;
            float a = Bs[co];
            #pragma unroll
            for (int k = 0; k < 27; ++k) a += v[k] * Wr[co * 27 + k];
            o[j] = f2bf(a);
        }
        *(ushort8*)(op + g * 8) = o;
    }
}

// ---------------- channels-last instance-norm: partial sums ----------------
// x: [B][P][C] bf16, P = PB*SPLITS. grid = B*SPLITS.
template <int C, int PB, int SPLITS>
__global__ LB void k_stats_cl(const ushort* __restrict__ x,
                              float* __restrict__ psum, float* __restrict__ pss) {
    __shared__ float lsum[C], lss[C];
    int b = blockIdx.x / SPLITS, sp = blockIdx.x % SPLITS;
    int t = threadIdx.x;
    if (t < C) { lsum[t] = 0.f; lss[t] = 0.f; }
    __syncthreads();
    constexpr int CG = C / 8;
    constexpr int PO = 256 / CG;
    int c0 = (t % CG) * 8;
    int po = t / CG;
    float s[8], ss[8];
    #pragma unroll
    for (int k = 0; k < 8; ++k) { s[k] = 0.f; ss[k] = 0.f; }
    const ushort* base = x + ((long)b * SPLITS + sp) * (long)PB * C;
    for (int p = po; p < PB; p += PO) {
        ushort8 v = *(const ushort8*)(base + (long)p * C + c0);
        #pragma unroll
        for (int k = 0; k < 8; ++k) {
            float f = bf2f(v[k]);
            s[k] += f; ss[k] += f * f;
        }
    }
    #pragma unroll
    for (int k = 0; k < 8; ++k) {
        atomicAdd(&lsum[c0 + k], s[k]);
        atomicAdd(&lss[c0 + k], ss[k]);
    }
    __syncthreads();
    if (t < C) {
        psum[blockIdx.x * C + t] = lsum[t];
        pss[blockIdx.x * C + t] = lss[t];
    }
}

// ---------------- reduce partials -> mean/istd ----------------
template <int C, int SPLITS, int P>
__global__ LB void k_red_cl(const float* __restrict__ psum, const float* __restrict__ pss,
                            float* __restrict__ mean, float* __restrict__ istd) {
    int idx = blockIdx.x * 256 + threadIdx.x;   // B*C
    if (idx >= 8 * C) return;
    int b = idx / C, c = idx % C;
    float s = 0.f, ss = 0.f;
    for (int sp = 0; sp < SPLITS; ++sp) {
        s += psum[(b * SPLITS + sp) * C + c];
        ss += pss[(b * SPLITS + sp) * C + c];
    }
    float m = s / (float)P;
    float v = ss / (float)P - m * m;
    mean[idx] = m;
    istd[idx] = rsqrtf(v + 1e-5f);
}

// ---------------- normalize + leaky-relu in place, channels-last bf16 ----------------
template <int C, int P>
__global__ LB void k_nl_cl(ushort* __restrict__ x, const float* __restrict__ mean,
                           const float* __restrict__ istd) {
    long e = ((long)blockIdx.x * 256 + threadIdx.x) * 8;
    int c0 = (int)(e % C);
    int b = (int)(e / ((long)P * C));
    ushort8 v = *(ushort8*)(x + e);
    const float* mp = mean + b * C + c0;
    const float* ip = istd + b * C + c0;
    #pragma unroll
    for (int k = 0; k < 8; ++k) {
        float u = (bf2f(v[k]) - mp[k]) * ip[k];
        u = u > 0.f ? u : 0.2f * u;
        v[k] = f2bf(u);
    }
    *(ushort8*)(x + e) = v;
}

// ---------------- weight transposes ----------------
__global__ LB void k_wt2(const float* __restrict__ w, ushort* __restrict__ wt) {
    int e = blockIdx.x * 256 + threadIdx.x;    // 18,432 = [9][64][32]
    int ci = e & 31, co = (e >> 5) & 63, tap = e >> 11;
    wt[e] = f2bf(w[(co * 32 + ci) * 9 + tap]);
}
__global__ LB void k_wt3(const float* __restrict__ w, ushort* __restrict__ wt) {
    int e = blockIdx.x * 256 + threadIdx.x;    // 73,728 = [9][128][64]
    int ci = e & 63, co = (e >> 6) & 127, tap = e >> 13;
    wt[e] = f2bf(w[(co * 64 + ci) * 9 + tap]);
}
__global__ LB void k_wt4(const float* __restrict__ w, ushort* __restrict__ wt) {
    int e = blockIdx.x * 256 + threadIdx.x;    // 294,912 = [9][256][128] (w4 is Cin,Cout,kh,kw)
    int ci = e & 127, co = (e >> 7) & 255, tap = e >> 15;
    wt[e] = f2bf(w[ci * 2304 + co * 9 + tap]);
}
__global__ LB void k_wt5(const float* __restrict__ w, ushort* __restrict__ wt) {
    int e = blockIdx.x * 256 + threadIdx.x;    // 1,179,648 = [9][512][256]
    int ci = e & 255, co = (e >> 8) & 511, tap = e >> 17;
    wt[e] = f2bf(w[(co * 256 + ci) * 9 + tap]);
}

// ---------------- conv2 MFMA: [8,256,256,32] -> [8,128,128,64], s2 p1 zero-pad ----------------
// grid = b*128 rows; 4 waves x 32 cols; wave: 64co x 32pos; K = 32ci x 9 taps
__global__ LB void k_conv2m(const ushort* __restrict__ xin, const ushort* __restrict__ wt,
                            const float* __restrict__ bias, ushort* __restrict__ xout) {
    int bx = blockIdx.x;
    int y = bx & 127, b = bx >> 7;
    int t = threadIdx.x, w = t >> 6, lane = t & 63;
    int col0 = w * 32;
    int lanep = lane & 15, hi = lane >> 4;

    f32x4 acc[4][2];
    #pragma unroll
    for (int m = 0; m < 4; ++m)
        #pragma unroll
        for (int n = 0; n < 2; ++n) acc[m][n] = (f32x4){0.f, 0.f, 0.f, 0.f};

    #pragma unroll
    for (int ky = 0; ky < 3; ++ky) {
        int iy = 2 * y + ky - 1;
        if (iy < 0) continue;                 // uniform; iy <= 255 always
        #pragma unroll
        for (int kx = 0; kx < 3; ++kx) {
            int tap = ky * 3 + kx;
            const ushort* wb = wt + ((tap * 64 + lanep) << 5) + hi * 8;
            frag16 av[4];
            #pragma unroll
            for (int m = 0; m < 4; ++m) av[m] = *(const frag16*)(wb + ((m * 16) << 5));
            frag16 bv[2];
            #pragma unroll
            for (int n = 0; n < 2; ++n) {
                int xo = col0 + n * 16 + lanep;
                int ix = 2 * xo + kx - 1;
                frag16 vv = (frag16)(short)0;
                if (ix >= 0)
                    vv = *(const frag16*)(xin + ((((long)(b * 256 + iy)) << 8) + ix) * 32 + hi * 8);
                bv[n] = vv;
            }
            #pragma unroll
            for (int m = 0; m < 4; ++m)
                #pragma unroll
                for (int n = 0; n < 2; ++n)
                    acc[m][n] = __builtin_amdgcn_mfma_f32_16x16x32_bf16(av[m], bv[n], acc[m][n], 0, 0, 0);
        }
    }
    float bvv[4][4];
    #pragma unroll
    for (int m = 0; m < 4; ++m)
        #pragma unroll
        for (int r = 0; r < 4; ++r) bvv[m][r] = bias[m * 16 + hi * 4 + r];
    #pragma unroll
    for (int n = 0; n < 2; ++n) {
        int xo = col0 + n * 16 + lanep;
        long pb = ((((long)(b * 128 + y)) << 7) + xo) * 64 + hi * 4;
        #pragma unroll
        for (int m = 0; m < 4; ++m) {
            ushort4 o;
            o.x = f2bf(acc[m][n][0] + bvv[m][0]);
            o.y = f2bf(acc[m][n][1] + bvv[m][1]);
            o.z = f2bf(acc[m][n][2] + bvv[m][2]);
            o.w = f2bf(acc[m][n][3] + bvv[m][3]);
            *(ushort4*)(xout + pb + m * 16) = o;
        }
    }
}

// ---------------- conv3 MFMA: [8,128,128,64] -> [8,64,64,128], s2 p1 zero-pad ----------------
// grid = b*64 rows; 4 waves = 2 co-tiles x 2 col-halves; wave: 64co x 32pos; K = 64ci x 9 taps
__global__ LB void k_conv3m(const ushort* __restrict__ xin, const ushort* __restrict__ wt,
                            const float* __restrict__ bias, ushort* __restrict__ xout) {
    int bx = blockIdx.x;
    int y = bx & 63, b = bx >> 6;
    int t = threadIdx.x, w = t >> 6, lane = t & 63;
    int co0 = (w >> 1) * 64;
    int col0 = (w & 1) * 32;
    int lanep = lane & 15, hi = lane >> 4;

    f32x4 acc[4][2];
    #pragma unroll
    for (int m = 0; m < 4; ++m)
        #pragma unroll
        for (int n = 0; n < 2; ++n) acc[m][n] = (f32x4){0.f, 0.f, 0.f, 0.f};

    #pragma unroll
    for (int ky = 0; ky < 3; ++ky) {
        int iy = 2 * y + ky - 1;
        if (iy < 0) continue;                 // uniform; iy <= 127 always
        #pragma unroll
        for (int kx = 0; kx < 3; ++kx) {
            int tap = ky * 3 + kx;
            #pragma unroll
            for (int ck = 0; ck < 2; ++ck) {
                int ci0 = ck * 32;
                const ushort* wb = wt + ((tap * 128 + co0 + lanep) << 6) + ci0 + hi * 8;
                frag16 av[4];
                #pragma unroll
                for (int m = 0; m < 4; ++m) av[m] = *(const frag16*)(wb + ((m * 16) << 6));
                frag16 bv[2];
                #pragma unroll
                for (int n = 0; n < 2; ++n) {
                    int xo = col0 + n * 16 + lanep;
                    int ix = 2 * xo + kx - 1;
                    frag16 vv = (frag16)(short)0;
                    if (ix >= 0)
                        vv = *(const frag16*)(xin + ((((long)(b * 128 + iy)) << 7) + ix) * 64 + ci0 + hi * 8);
                    bv[n] = vv;
                }
                #pragma unroll
                for (int m = 0; m < 4; ++m)
                    #pragma unroll
                    for (int n = 0; n < 2; ++n)
                        acc[m][n] = __builtin_amdgcn_mfma_f32_16x16x32_bf16(av[m], bv[n], acc[m][n], 0, 0, 0);
            }
        }
    }
    float bvv[4][4];
    #pragma unroll
    for (int m = 0; m < 4; ++m)
        #pragma unroll
        for (int r = 0; r < 4; ++r) bvv[m][r] = bias[co0 + m * 16 + hi * 4 + r];
    #pragma unroll
    for (int n = 0; n < 2; ++n) {
        int xo = col0 + n * 16 + lanep;
        long pb = ((((long)(b * 64 + y)) << 6) + xo) * 128 + co0 + hi * 4;
        #pragma unroll
        for (int m = 0; m < 4; ++m) {
            ushort4 o;
            o.x = f2bf(acc[m][n][0] + bvv[m][0]);
            o.y = f2bf(acc[m][n][1] + bvv[m][1]);
            o.z = f2bf(acc[m][n][2] + bvv[m][2]);
            o.w = f2bf(acc[m][n][3] + bvv[m][3]);
            *(ushort4*)(xout + pb + m * 16) = o;
        }
    }
}

// ---------------- convT4 MFMA (parity decomposition): [8,64,64,128] -> [8,128,128,256] ----
__global__ LB void k_convt4m(const ushort* __restrict__ x3l, const ushort* __restrict__ wt,
                             const float* __restrict__ bias, ushort* __restrict__ xl) {
    int bx = blockIdx.x;
    int parity = bx & 3;
    int py = parity >> 1, px = parity & 1;
    int rg = (bx >> 2) & 15;
    int ct = (bx >> 6) & 3;
    int b  = bx >> 8;
    int co0 = ct * 64;
    int t = threadIdx.x;
    int w = t >> 6;
    int ip = rg * 4 + w;
    int lane = t & 63;
    int lanep = lane & 15;
    int hi = lane >> 4;
    int laneq = hi * 8;

    f32x4 acc[4][4];
    #pragma unroll
    for (int m = 0; m < 4; ++m)
        #pragma unroll
        for (int n = 0; n < 4; ++n) acc[m][n] = (f32x4){0.f, 0.f, 0.f, 0.f};

    #pragma unroll
    for (int ky = 0; ky < 3; ++ky) {
        if (((ky + py) & 1) == 0) continue;
        int i = ip + ((py == 1 && ky == 0) ? 1 : 0);
        if (i >= 64) continue;
        #pragma unroll
        for (int kx = 0; kx < 3; ++kx) {
            if (((kx + px) & 1) == 0) continue;
            int dxp = (px == 1 && kx == 0) ? 1 : 0;
            int tap = ky * 3 + kx;
            const ushort* wbase = wt + (((long)tap * 256 + co0 + lanep) << 7) + laneq;
            const ushort* xbase = x3l + ((((long)b << 12) + (i << 6)) << 7) + laneq;
            #pragma unroll
            for (int ci0 = 0; ci0 < 128; ci0 += 32) {
                frag16 av[4], bv[4];
                #pragma unroll
                for (int m = 0; m < 4; ++m)
                    av[m] = *(const frag16*)(wbase + ((m * 16) << 7) + ci0);
                #pragma unroll
                for (int n = 0; n < 4; ++n) {
                    int j = n * 16 + lanep + dxp;
                    bool valid = j < 64;
                    frag16 v = *(const frag16*)(xbase + ((valid ? j : 63) << 7) + ci0);
                    if (!valid) v = (frag16)(short)0;
                    bv[n] = v;
                }
                #pragma unroll
                for (int m = 0; m < 4; ++m)
                    #pragma unroll
                    for (int n = 0; n < 4; ++n)
                        acc[m][n] = __builtin_amdgcn_mfma_f32_16x16x32_bf16(av[m], bv[n], acc[m][n], 0, 0, 0);
            }
        }
    }

    float bvv[4][4];
    #pragma unroll
    for (int m = 0; m < 4; ++m)
        #pragma unroll
        for (int r = 0; r < 4; ++r)
            bvv[m][r] = bias[co0 + m * 16 + hi * 4 + r];
    int y = 2 * ip + py;
    #pragma unroll
    for (int n = 0; n < 4; ++n) {
        int x = 2 * (n * 16 + lanep) + px;
        long pb = ((((long)b << 14) + (y << 7) + x) << 8) + co0 + hi * 4;
        #pragma unroll
        for (int m = 0; m < 4; ++m) {
            ushort4 o;
            o.x = f2bf(acc[m][n][0] + bvv[m][0]);
            o.y = f2bf(acc[m][n][1] + bvv[m][1]);
            o.z = f2bf(acc[m][n][2] + bvv[m][2]);
            o.w = f2bf(acc[m][n][3] + bvv[m][3]);
            *(ushort4*)(xl + pb + m * 16) = o;
        }
    }
}

// ---------------- label map @128x128 + per-class counts ----------------
__global__ LB void k_label(const float* __restrict__ segmap, int* __restrict__ lab,
                           int* __restrict__ counts) {
    __shared__ int h[S];
    if (threadIdx.x < S) h[threadIdx.x] = 0;
    __syncthreads();
    int idx = blockIdx.x * 256 + threadIdx.x;        // 8*128*128
    int x = idx & 127, y = (idx >> 7) & 127, b = idx >> 14;
    const float* sp = segmap + (long)b * S * 65536 + (y << 1) * 256 + (x << 1);
    int s = 0;
    for (int c = 0; c < S; ++c) {
        if (sp[c * 65536] > 0.f) { s = c; break; }
    }
    lab[idx] = s;
    atomicAdd(&h[s], 1);
    __syncthreads();
    if (threadIdx.x < S) atomicAdd(&counts[b * S + threadIdx.x], h[threadIdx.x]);
}

// ---------------- conv5 MFMA implicit GEMM + bias + tanh + masked class-sum ----------------
__global__ LB void k_conv5m(const ushort* __restrict__ xl, const ushort* __restrict__ wt,
                            const float* __restrict__ bias, const int* __restrict__ lab,
                            float* __restrict__ sumbuf) {
    __shared__ __align__(16) ushort Xs[520 * 40];   // [4 rows][130 cols][40 ci-pad]
    __shared__ float part[S * 64];

    int bx = blockIdx.x;
    int yp = bx & 63;
    int ct = (bx >> 6) & 7;
    int b  = bx >> 9;
    int y0 = yp * 2, co0 = ct * 64;
    int t = threadIdx.x;
    int w = t >> 6;
    int lane = t & 63;
    int row_w = w >> 1;
    int col0 = (w & 1) * 64;
    int lanep = lane & 15;
    int laneq = (lane >> 4) * 8;
    int hi = lane >> 4;

    f32x4 acc[4][4];
    #pragma unroll
    for (int m = 0; m < 4; ++m)
        #pragma unroll
        for (int n = 0; n < 4; ++n) acc[m][n] = (f32x4){0.f, 0.f, 0.f, 0.f};

    for (int ci0 = 0; ci0 < 256; ci0 += 32) {
        for (int e = t; e < 2080; e += 256) {
            int p = e >> 2, q = e & 3;
            int r = p / 130, x = p - r * 130;
            int gy = y0 - 1 + r; gy = gy < 0 ? -gy : (gy > 127 ? 254 - gy : gy);
            int gx = x - 1;      gx = gx < 0 ? -gx : (gx > 127 ? 254 - gx : gx);
            frag16 v = *(const frag16*)(xl + ((((long)b << 14) + (gy << 7) + gx) << 8) + ci0 + q * 8);
            *(frag16*)(Xs + p * 40 + q * 8) = v;
        }
        __syncthreads();

        frag16 a_cur[4], a_nxt[4];
        #pragma unroll
        for (int m = 0; m < 4; ++m)
            a_cur[m] = *(const frag16*)(wt + (co0 + m * 16 + lanep) * 256 + ci0 + laneq);

        #pragma unroll
        for (int tap = 0; tap < 9; ++tap) {
            int ky = tap / 3, kx = tap % 3;
            if (tap < 8) {
                #pragma unroll
                for (int m = 0; m < 4; ++m)
                    a_nxt[m] = *(const frag16*)(wt + ((tap + 1) * 512 + co0 + m * 16 + lanep) * 256 + ci0 + laneq);
            }
            frag16 bfr[4];
            int rbase = ((row_w + ky) * 130 + col0 + kx + lanep) * 40 + laneq;
            #pragma unroll
            for (int n = 0; n < 4; ++n)
                bfr[n] = *(const frag16*)(Xs + rbase + n * (16 * 40));
            #pragma unroll
            for (int m = 0; m < 4; ++m)
                #pragma unroll
                for (int n = 0; n < 4; ++n)
                    acc[m][n] = __builtin_amdgcn_mfma_f32_16x16x32_bf16(a_cur[m], bfr[n], acc[m][n], 0, 0, 0);
            #pragma unroll
            for (int m = 0; m < 4; ++m) a_cur[m] = a_nxt[m];
        }
        __syncthreads();
    }

    float bv[4][4];
    #pragma unroll
    for (int m = 0; m < 4; ++m)
        #pragma unroll
        for (int r = 0; r < 4; ++r)
            bv[m][r] = bias[co0 + m * 16 + hi * 4 + r];

    for (int e = t; e < S * 64; e += 256) part[e] = 0.f;
    __syncthreads();

    int y = y0 + row_w;
    #pragma unroll
    for (int n = 0; n < 4; ++n) {
        int x = col0 + n * 16 + lanep;
        int s = lab[(b << 14) + (y << 7) + x];
        #pragma unroll
        for (int m = 0; m < 4; ++m)
            #pragma unroll
            for (int r = 0; r < 4; ++r)
                atomicAdd(&part[s * 64 + m * 16 + hi * 4 + r], tanhf(acc[m][n][r] + bv[m][r]));
    }
    __syncthreads();
    for (int e = t; e < S * 64; e += 256) {
        int s = e >> 6, col = e & 63;
        atomicAdd(&sumbuf[((b * S + s) << 9) + co0 + col], part[e]);
    }
}

// ---------------- finalize ----------------
__global__ LB void k_final(const float* __restrict__ sumbuf, const int* __restrict__ counts,
                           float* __restrict__ out) {
    int idx = blockIdx.x * 256 + threadIdx.x;   // 8*19*512
    int tt = idx >> 9;
    int s = tt % S, b = tt / S;
    int cnt = counts[b * S + s];
    out[idx] = cnt > 0 ? sumbuf[idx] / (float)cnt : 0.f;
}

extern "C" void kernel_launch(void* const* d_in, const int* in_sizes, int n_in,
                              void* d_out, int out_size, void* d_ws, size_t ws_size,
                              hipStream_t stream) {
    const float* input  = (const float*)d_in[0];
    const float* segmap = (const float*)d_in[1];
    const float* w1 = (const float*)d_in[2];  const float* b1 = (const float*)d_in[3];
    const float* w2 = (const float*)d_in[4];  const float* b2 = (const float*)d_in[5];
    const float* w3 = (const float*)d_in[6];  const float* b3 = (const float*)d_in[7];
    const float* w4 = (const float*)d_in[8];  const float* b4 = (const float*)d_in[9];
    const float* w5 = (const float*)d_in[10]; const float* b5 = (const float*)d_in[11];
    float* out = (float*)d_out;

    float* ws = (float*)d_ws;
    ushort* xl    = (ushort*)ws;                  // [8,128,128,256] bf16 = 16,777,216 f32 slots
    ushort* x1l   = (ushort*)(ws + 16777216);     // [8,256,256,32]  = 8,388,608 slots
    ushort* x2l   = (ushort*)(ws + 25165824);     // [8,128,128,64]  = 4,194,304 slots
    ushort* x3l   = (ushort*)(ws + 29360128);     // [8,64,64,128]   = 2,097,152 slots
    float* sumbuf = ws + 31457280;                // 77,824
    float* mean   = ws + 31535104;                // 2,048
    float* istd   = ws + 31537152;                // 2,048
    int*   lab    = (int*)(ws + 31539200);        // 131,072
    int*   counts = (int*)(ws + 31670272);        // 256
    ushort* wt5   = (ushort*)(ws + 31670528);     // 1,179,648 bf16 (589,824 slots)
    ushort* wt4t  = (ushort*)(ws + 32260352);     // 294,912 bf16 (147,456 slots)
    ushort* wt2   = (ushort*)(ws + 32407808);     // 18,432 bf16 (9,216 slots)
    ushort* wt3   = (ushort*)(ws + 32417024);     // 73,728 bf16 (36,864 slots)
    float* psum   = ws + 32453888;                // 65,536
    float* pss    = ws + 32519424;                // 65,536

    hipMemsetAsync(sumbuf, 0, 77824 * sizeof(float), stream);
    hipMemsetAsync(counts, 0, 256 * sizeof(int), stream);

    k_wt5<<<4608, 256, 0, stream>>>(w5, wt5);
    k_wt4<<<1152, 256, 0, stream>>>(w4, wt4t);
    k_wt2<<<72, 256, 0, stream>>>(w2, wt2);
    k_wt3<<<288, 256, 0, stream>>>(w3, wt3);
    // layer 1
    k_conv1cl<<<2048, 256, 0, stream>>>(input, w1, b1, x1l);
    k_stats_cl<32, 1024, 64><<<512, 256, 0, stream>>>(x1l, psum, pss);
    k_red_cl<32, 64, 65536><<<1, 256, 0, stream>>>(psum, pss, mean, istd);
    k_nl_cl<32, 65536><<<8192, 256, 0, stream>>>(x1l, mean, istd);
    // layer 2
    k_conv2m<<<1024, 256, 0, stream>>>(x1l, wt2, b2, x2l);
    k_stats_cl<64, 512, 32><<<256, 256, 0, stream>>>(x2l, psum, pss);
    k_red_cl<64, 32, 16384><<<2, 256, 0, stream>>>(psum, pss, mean, istd);
    k_nl_cl<64, 16384><<<4096, 256, 0, stream>>>(x2l, mean, istd);
    // layer 3
    k_conv3m<<<512, 256, 0, stream>>>(x2l, wt3, b3, x3l);
    k_stats_cl<128, 256, 16><<<128, 256, 0, stream>>>(x3l, psum, pss);
    k_red_cl<128, 16, 4096><<<4, 256, 0, stream>>>(psum, pss, mean, istd);
    k_nl_cl<128, 4096><<<2048, 256, 0, stream>>>(x3l, mean, istd);
    // layer 4 (transpose conv)
    k_convt4m<<<2048, 256, 0, stream>>>(x3l, wt4t, b4, xl);
    k_stats_cl<256, 512, 32><<<256, 256, 0, stream>>>(xl, psum, pss);
    k_red_cl<256, 32, 16384><<<8, 256, 0, stream>>>(psum, pss, mean, istd);
    k_nl_cl<256, 16384><<<16384, 256, 0, stream>>>(xl, mean, istd);
    // label map + counts
    k_label<<<512, 256, 0, stream>>>(segmap, lab, counts);
    // layer 5: MFMA implicit GEMM fused with masked class-sum
    k_conv5m<<<4096, 256, 0, stream>>>(xl, wt5, b5, lab, sumbuf);
    // finalize
    k_final<<<304, 256, 0, stream>>>(sumbuf, counts, out);
}

// Round 5
// 1281.613 us; speedup vs baseline: 11.7505x; 1.0432x over previous
//
#include <hip/hip_runtime.h>

#define LB __launch_bounds__(256)

constexpr int S = 19;

typedef __attribute__((ext_vector_type(8))) short frag16;   // 8 bf16 (4 VGPR)
typedef __attribute__((ext_vector_type(8))) ushort ushort8;
typedef __attribute__((ext_vector_type(4))) float f32x4;

__device__ __forceinline__ int reflect256(int i) { return i < 0 ? -i : (i > 255 ? 510 - i : i); }
__device__ __forceinline__ int reflect128(int i) { return i < 0 ? -i : (i > 127 ? 254 - i : i); }

__device__ __forceinline__ ushort f2bf(float f) {
    union { float f; uint u; } a; a.f = f;
    uint r = a.u + 0x7fffu + ((a.u >> 16) & 1u);   // round-nearest-even
    return (ushort)(r >> 16);
}
__device__ __forceinline__ float bf2f(ushort u) {
    union { uint u; float f; } a; a.u = ((uint)u) << 16; return a.f;
}

// ---------------- conv1: [8,3,256,256] f32 -> [8,256,256,32] bf16 CL, reflect pad ----------------
__global__ LB void k_conv1cl(const float* __restrict__ in, const float* __restrict__ w,
                             const float* __restrict__ bias, ushort* __restrict__ out) {
    __shared__ float Wr[864];   // [co][ci*9+tap]
    __shared__ float Bs[32];
    int t = threadIdx.x;
    for (int e = t; e < 864; e += 256) Wr[e] = w[e];
    if (t < 32) Bs[t] = bias[t];
    __syncthreads();
    int idx = blockIdx.x * 256 + t;          // 524288 pixels
    int x = idx & 255, y = (idx >> 8) & 255, b = idx >> 16;
    float v[27];
    #pragma unroll
    for (int ci = 0; ci < 3; ++ci) {
        const float* ip = in + ((b * 3 + ci) << 16);
        #pragma unroll
        for (int ky = 0; ky < 3; ++ky) {
            int iy = reflect256(y + ky - 1);
            #pragma unroll
            for (int kx = 0; kx < 3; ++kx) {
                int ix = reflect256(x + kx - 1);
                v[ci * 9 + ky * 3 + kx] = ip[(iy << 8) + ix];
            }
        }
    }
    ushort* op = out + (long)idx * 32;
    #pragma unroll
    for (int g = 0; g < 4; ++g) {
        ushort8 o;
        #pragma unroll
        for (int j = 0; j < 8; ++j) {
            int co = g * 8 + j;
            float a = Bs[co];
            #pragma unroll
            for (int k = 0; k < 27; ++k) a += v[k] * Wr[co * 27 + k];
            o[j] = f2bf(a);
        }
        *(ushort8*)(op + g * 8) = o;
    }
}

// ---------------- channels-last instance-norm: partial sums ----------------
template <int C, int PB, int SPLITS>
__global__ LB void k_stats_cl(const ushort* __restrict__ x,
                              float* __restrict__ psum, float* __restrict__ pss) {
    __shared__ float lsum[C], lss[C];
    int b = blockIdx.x / SPLITS, sp = blockIdx.x % SPLITS;
    int t = threadIdx.x;
    if (t < C) { lsum[t] = 0.f; lss[t] = 0.f; }
    __syncthreads();
    constexpr int CG = C / 8;
    constexpr int PO = 256 / CG;
    int c0 = (t % CG) * 8;
    int po = t / CG;
    float s[8], ss[8];
    #pragma unroll
    for (int k = 0; k < 8; ++k) { s[k] = 0.f; ss[k] = 0.f; }
    const ushort* base = x + ((long)b * SPLITS + sp) * (long)PB * C;
    for (int p = po; p < PB; p += PO) {
        ushort8 v = *(const ushort8*)(base + (long)p * C + c0);
        #pragma unroll
        for (int k = 0; k < 8; ++k) {
            float f = bf2f(v[k]);
            s[k] += f; ss[k] += f * f;
        }
    }
    #pragma unroll
    for (int k = 0; k < 8; ++k) {
        atomicAdd(&lsum[c0 + k], s[k]);
        atomicAdd(&lss[c0 + k], ss[k]);
    }
    __syncthreads();
    if (t < C) {
        psum[blockIdx.x * C + t] = lsum[t];
        pss[blockIdx.x * C + t] = lss[t];
    }
}

// ---------------- reduce partials -> mean/istd ----------------
template <int C, int SPLITS, int P>
__global__ LB void k_red_cl(const float* __restrict__ psum, const float* __restrict__ pss,
                            float* __restrict__ mean, float* __restrict__ istd) {
    int idx = blockIdx.x * 256 + threadIdx.x;   // B*C
    if (idx >= 8 * C) return;
    int b = idx / C, c = idx % C;
    float s = 0.f, ss = 0.f;
    for (int sp = 0; sp < SPLITS; ++sp) {
        s += psum[(b * SPLITS + sp) * C + c];
        ss += pss[(b * SPLITS + sp) * C + c];
    }
    float m = s / (float)P;
    float v = ss / (float)P - m * m;
    mean[idx] = m;
    istd[idx] = rsqrtf(v + 1e-5f);
}

// ---------------- normalize + leaky-relu in place, channels-last bf16 ----------------
template <int C, int P>
__global__ LB void k_nl_cl(ushort* __restrict__ x, const float* __restrict__ mean,
                           const float* __restrict__ istd) {
    long e = ((long)blockIdx.x * 256 + threadIdx.x) * 8;
    int c0 = (int)(e % C);
    int b = (int)(e / ((long)P * C));
    ushort8 v = *(ushort8*)(x + e);
    const float* mp = mean + b * C + c0;
    const float* ip = istd + b * C + c0;
    #pragma unroll
    for (int k = 0; k < 8; ++k) {
        float u = (bf2f(v[k]) - mp[k]) * ip[k];
        u = u > 0.f ? u : 0.2f * u;
        v[k] = f2bf(u);
    }
    *(ushort8*)(x + e) = v;
}

// ---------------- all weight transposes in one kernel ----------------
// wt2 [9][64][32] | wt3 [9][128][64] | wt4 [9][256][128] | wt5 [9][512][256]
__global__ LB void k_wtall(const float* __restrict__ w2, const float* __restrict__ w3,
                           const float* __restrict__ w4, const float* __restrict__ w5,
                           ushort* __restrict__ t2, ushort* __restrict__ t3,
                           ushort* __restrict__ t4, ushort* __restrict__ t5) {
    int e = blockIdx.x * 256 + threadIdx.x;    // 1,566,720 total
    if (e < 18432) {
        int ci = e & 31, co = (e >> 5) & 63, tap = e >> 11;
        t2[e] = f2bf(w2[(co * 32 + ci) * 9 + tap]);
    } else if (e < 18432 + 73728) {
        int e2 = e - 18432;
        int ci = e2 & 63, co = (e2 >> 6) & 127, tap = e2 >> 13;
        t3[e2] = f2bf(w3[(co * 64 + ci) * 9 + tap]);
    } else if (e < 18432 + 73728 + 294912) {
        int e3 = e - (18432 + 73728);
        int ci = e3 & 127, co = (e3 >> 7) & 255, tap = e3 >> 15;
        t4[e3] = f2bf(w4[ci * 2304 + co * 9 + tap]);   // w4 is (Cin,Cout,kh,kw)
    } else {
        int e4 = e - (18432 + 73728 + 294912);
        int ci = e4 & 255, co = (e4 >> 8) & 511, tap = e4 >> 17;
        t5[e4] = f2bf(w5[(co * 256 + ci) * 9 + tap]);
    }
}

// ---------------- conv2 MFMA: [8,256,256,32] -> [8,128,128,64], s2 p1 zero-pad ----------------
__global__ LB void k_conv2m(const ushort* __restrict__ xin, const ushort* __restrict__ wt,
                            const float* __restrict__ bias, ushort* __restrict__ xout) {
    int bx = blockIdx.x;
    int y = bx & 127, b = bx >> 7;
    int t = threadIdx.x, w = t >> 6, lane = t & 63;
    int col0 = w * 32;
    int lanep = lane & 15, hi = lane >> 4;

    f32x4 acc[4][2];
    #pragma unroll
    for (int m = 0; m < 4; ++m)
        #pragma unroll
        for (int n = 0; n < 2; ++n) acc[m][n] = (f32x4){0.f, 0.f, 0.f, 0.f};

    #pragma unroll
    for (int ky = 0; ky < 3; ++ky) {
        int iy = 2 * y + ky - 1;
        if (iy < 0) continue;
        #pragma unroll
        for (int kx = 0; kx < 3; ++kx) {
            int tap = ky * 3 + kx;
            const ushort* wb = wt + ((tap * 64 + lanep) << 5) + hi * 8;
            frag16 av[4];
            #pragma unroll
            for (int m = 0; m < 4; ++m) av[m] = *(const frag16*)(wb + ((m * 16) << 5));
            frag16 bv[2];
            #pragma unroll
            for (int n = 0; n < 2; ++n) {
                int xo = col0 + n * 16 + lanep;
                int ix = 2 * xo + kx - 1;
                frag16 vv = (frag16)(short)0;
                if (ix >= 0)
                    vv = *(const frag16*)(xin + ((((long)(b * 256 + iy)) << 8) + ix) * 32 + hi * 8);
                bv[n] = vv;
            }
            #pragma unroll
            for (int m = 0; m < 4; ++m)
                #pragma unroll
                for (int n = 0; n < 2; ++n)
                    acc[m][n] = __builtin_amdgcn_mfma_f32_16x16x32_bf16(av[m], bv[n], acc[m][n], 0, 0, 0);
        }
    }
    float bvv[4][4];
    #pragma unroll
    for (int m = 0; m < 4; ++m)
        #pragma unroll
        for (int r = 0; r < 4; ++r) bvv[m][r] = bias[m * 16 + hi * 4 + r];
    #pragma unroll
    for (int n = 0; n < 2; ++n) {
        int xo = col0 + n * 16 + lanep;
        long pb = ((((long)(b * 128 + y)) << 7) + xo) * 64 + hi * 4;
        #pragma unroll
        for (int m = 0; m < 4; ++m) {
            ushort4 o;
            o.x = f2bf(acc[m][n][0] + bvv[m][0]);
            o.y = f2bf(acc[m][n][1] + bvv[m][1]);
            o.z = f2bf(acc[m][n][2] + bvv[m][2]);
            o.w = f2bf(acc[m][n][3] + bvv[m][3]);
            *(ushort4*)(xout + pb + m * 16) = o;
        }
    }
}

// ---------------- conv3 MFMA: [8,128,128,64] -> [8,64,64,128], s2 p1 zero-pad ----------------
__global__ LB void k_conv3m(const ushort* __restrict__ xin, const ushort* __restrict__ wt,
                            const float* __restrict__ bias, ushort* __restrict__ xout) {
    int bx = blockIdx.x;
    int y = bx & 63, b = bx >> 6;
    int t = threadIdx.x, w = t >> 6, lane = t & 63;
    int co0 = (w >> 1) * 64;
    int col0 = (w & 1) * 32;
    int lanep = lane & 15, hi = lane >> 4;

    f32x4 acc[4][2];
    #pragma unroll
    for (int m = 0; m < 4; ++m)
        #pragma unroll
        for (int n = 0; n < 2; ++n) acc[m][n] = (f32x4){0.f, 0.f, 0.f, 0.f};

    #pragma unroll
    for (int ky = 0; ky < 3; ++ky) {
        int iy = 2 * y + ky - 1;
        if (iy < 0) continue;
        #pragma unroll
        for (int kx = 0; kx < 3; ++kx) {
            int tap = ky * 3 + kx;
            #pragma unroll
            for (int ck = 0; ck < 2; ++ck) {
                int ci0 = ck * 32;
                const ushort* wb = wt + ((tap * 128 + co0 + lanep) << 6) + ci0 + hi * 8;
                frag16 av[4];
                #pragma unroll
                for (int m = 0; m < 4; ++m) av[m] = *(const frag16*)(wb + ((m * 16) << 6));
                frag16 bv[2];
                #pragma unroll
                for (int n = 0; n < 2; ++n) {
                    int xo = col0 + n * 16 + lanep;
                    int ix = 2 * xo + kx - 1;
                    frag16 vv = (frag16)(short)0;
                    if (ix >= 0)
                        vv = *(const frag16*)(xin + ((((long)(b * 128 + iy)) << 7) + ix) * 64 + ci0 + hi * 8);
                    bv[n] = vv;
                }
                #pragma unroll
                for (int m = 0; m < 4; ++m)
                    #pragma unroll
                    for (int n = 0; n < 2; ++n)
                        acc[m][n] = __builtin_amdgcn_mfma_f32_16x16x32_bf16(av[m], bv[n], acc[m][n], 0, 0, 0);
            }
        }
    }
    float bvv[4][4];
    #pragma unroll
    for (int m = 0; m < 4; ++m)
        #pragma unroll
        for (int r = 0; r < 4; ++r) bvv[m][r] = bias[co0 + m * 16 + hi * 4 + r];
    #pragma unroll
    for (int n = 0; n < 2; ++n) {
        int xo = col0 + n * 16 + lanep;
        long pb = ((((long)(b * 64 + y)) << 6) + xo) * 128 + co0 + hi * 4;
        #pragma unroll
        for (int m = 0; m < 4; ++m) {
            ushort4 o;
            o.x = f2bf(acc[m][n][0] + bvv[m][0]);
            o.y = f2bf(acc[m][n][1] + bvv[m][1]);
            o.z = f2bf(acc[m][n][2] + bvv[m][2]);
            o.w = f2bf(acc[m][n][3] + bvv[m][3]);
            *(ushort4*)(xout + pb + m * 16) = o;
        }
    }
}

// ---------------- convT4 MFMA (parity decomposition): [8,64,64,128] -> [8,128,128,256] ----
__global__ LB void k_convt4m(const ushort* __restrict__ x3l, const ushort* __restrict__ wt,
                             const float* __restrict__ bias, ushort* __restrict__ xl) {
    int bx = blockIdx.x;
    int parity = bx & 3;
    int py = parity >> 1, px = parity & 1;
    int rg = (bx >> 2) & 15;
    int ct = (bx >> 6) & 3;
    int b  = bx >> 8;
    int co0 = ct * 64;
    int t = threadIdx.x;
    int w = t >> 6;
    int ip = rg * 4 + w;
    int lane = t & 63;
    int lanep = lane & 15;
    int hi = lane >> 4;
    int laneq = hi * 8;

    f32x4 acc[4][4];
    #pragma unroll
    for (int m = 0; m < 4; ++m)
        #pragma unroll
        for (int n = 0; n < 4; ++n) acc[m][n] = (f32x4){0.f, 0.f, 0.f, 0.f};

    #pragma unroll
    for (int ky = 0; ky < 3; ++ky) {
        if (((ky + py) & 1) == 0) continue;
        int i = ip + ((py == 1 && ky == 0) ? 1 : 0);
        if (i >= 64) continue;
        #pragma unroll
        for (int kx = 0; kx < 3; ++kx) {
            if (((kx + px) & 1) == 0) continue;
            int dxp = (px == 1 && kx == 0) ? 1 : 0;
            int tap = ky * 3 + kx;
            const ushort* wbase = wt + (((long)tap * 256 + co0 + lanep) << 7) + laneq;
            const ushort* xbase = x3l + ((((long)b << 12) + (i << 6)) << 7) + laneq;
            #pragma unroll
            for (int ci0 = 0; ci0 < 128; ci0 += 32) {
                frag16 av[4], bv[4];
                #pragma unroll
                for (int m = 0; m < 4; ++m)
                    av[m] = *(const frag16*)(wbase + ((m * 16) << 7) + ci0);
                #pragma unroll
                for (int n = 0; n < 4; ++n) {
                    int j = n * 16 + lanep + dxp;
                    bool valid = j < 64;
                    frag16 v = *(const frag16*)(xbase + ((valid ? j : 63) << 7) + ci0);
                    if (!valid) v = (frag16)(short)0;
                    bv[n] = v;
                }
                #pragma unroll
                for (int m = 0; m < 4; ++m)
                    #pragma unroll
                    for (int n = 0; n < 4; ++n)
                        acc[m][n] = __builtin_amdgcn_mfma_f32_16x16x32_bf16(av[m], bv[n], acc[m][n], 0, 0, 0);
            }
        }
    }

    float bvv[4][4];
    #pragma unroll
    for (int m = 0; m < 4; ++m)
        #pragma unroll
        for (int r = 0; r < 4; ++r)
            bvv[m][r] = bias[co0 + m * 16 + hi * 4 + r];
    int y = 2 * ip + py;
    #pragma unroll
    for (int n = 0; n < 4; ++n) {
        int x = 2 * (n * 16 + lanep) + px;
        long pb = ((((long)b << 14) + (y << 7) + x) << 8) + co0 + hi * 4;
        #pragma unroll
        for (int m = 0; m < 4; ++m) {
            ushort4 o;
            o.x = f2bf(acc[m][n][0] + bvv[m][0]);
            o.y = f2bf(acc[m][n][1] + bvv[m][1]);
            o.z = f2bf(acc[m][n][2] + bvv[m][2]);
            o.w = f2bf(acc[m][n][3] + bvv[m][3]);
            *(ushort4*)(xl + pb + m * 16) = o;
        }
    }
}

// ---------------- label map @128x128 + per-class counts ----------------
__global__ LB void k_label(const float* __restrict__ segmap, int* __restrict__ lab,
                           int* __restrict__ counts) {
    __shared__ int h[S];
    if (threadIdx.x < S) h[threadIdx.x] = 0;
    __syncthreads();
    int idx = blockIdx.x * 256 + threadIdx.x;        // 8*128*128
    int x = idx & 127, y = (idx >> 7) & 127, b = idx >> 14;
    const float* sp = segmap + (long)b * S * 65536 + (y << 1) * 256 + (x << 1);
    int s = 0;
    for (int c = 0; c < S; ++c) {
        if (sp[c * 65536] > 0.f) { s = c; break; }
    }
    lab[idx] = s;
    atomicAdd(&h[s], 1);
    __syncthreads();
    if (threadIdx.x < S) atomicAdd(&counts[b * S + threadIdx.x], h[threadIdx.x]);
}

// ---------------- conv5 MFMA implicit GEMM v2 + bias + tanh + masked class-sum ----------------
// xl: [8][128][128][256] bf16; wt: [9][512][256] bf16
// block (512 thr, 8 waves): b, co-tile 128, row-pair. Wave: 64co x (1row x 64col).
// Double-buffered LDS, T14 async-stage split (issue loads early, ds_write late).
__global__ void __launch_bounds__(512, 4)
k_conv5m(const ushort* __restrict__ xl, const ushort* __restrict__ wt,
         const float* __restrict__ bias, const int* __restrict__ lab,
         float* __restrict__ sumbuf) {
    // 2 buffers x [4 rows][130 cols][36 ci-pad] ushort = 74,880 B total
    __shared__ __align__(16) ushort Xs[2 * 18720];
    float* part = (float*)Xs;          // aliased after final compute barrier (needs 9,728 B)

    int bx = blockIdx.x;
    int yp = bx & 63;
    int ct = (bx >> 6) & 3;
    int b  = bx >> 8;
    int y0 = yp * 2;
    int t = threadIdx.x;
    int w = t >> 6;
    int lane = t & 63;
    int row_w = w & 1;                 // output row within pair
    int col0 = ((w >> 1) & 1) * 64;    // column half
    int com  = (w >> 2);               // co half within 128-tile
    int cob  = ct * 128 + com * 64;    // global co base for this wave
    int lanep = lane & 15;
    int hi = lane >> 4;
    int laneq = hi * 8;

    // staging geometry: iter i stages row i (gy = reflect(y0-1+i)), x = t>>2, q = t&3
    int sx = t >> 2;                   // 0..127 (image x)
    int sq = (t & 3) * 8;              // ci sub-offset
    int gyr[4];
    #pragma unroll
    for (int i = 0; i < 4; ++i) gyr[i] = reflect128(y0 - 1 + i);
    // tail (t<32): 2 boundary cols x 4 rows x 4 q
    int tl_side = t >> 4, tl_r = (t >> 2) & 3, tl_q = (t & 3) * 8;
    int tl_gx = tl_side ? 126 : 1;     // reflect of x=128 / x=-1
    int tl_c  = tl_side ? 129 : 0;     // staged col
    long xbase = ((long)b << 14);

    f32x4 acc[4][4];
    #pragma unroll
    for (int m = 0; m < 4; ++m)
        #pragma unroll
        for (int n = 0; n < 4; ++n) acc[m][n] = (f32x4){0.f, 0.f, 0.f, 0.f};

    frag16 g0, g1, g2, g3, gt;

    // ---- load chunk 0 ----
    #define LOADC(ci0)                                                                       \
        g0 = *(const frag16*)(xl + ((xbase + (gyr[0] << 7) + sx) << 8) + (ci0) + sq);        \
        g1 = *(const frag16*)(xl + ((xbase + (gyr[1] << 7) + sx) << 8) + (ci0) + sq);        \
        g2 = *(const frag16*)(xl + ((xbase + (gyr[2] << 7) + sx) << 8) + (ci0) + sq);        \
        g3 = *(const frag16*)(xl + ((xbase + (gyr[3] << 7) + sx) << 8) + (ci0) + sq);        \
        if (t < 32) gt = *(const frag16*)(xl + ((xbase + (gyr[tl_r] << 7) + tl_gx) << 8) + (ci0) + tl_q);

    #define WRITEC(buf)                                                                      \
        {                                                                                    \
            ushort* d = Xs + (buf) * 18720;                                                  \
            *(frag16*)(d + (0 * 130 + sx + 1) * 36 + sq) = g0;                               \
            *(frag16*)(d + (1 * 130 + sx + 1) * 36 + sq) = g1;                               \
            *(frag16*)(d + (2 * 130 + sx + 1) * 36 + sq) = g2;                               \
            *(frag16*)(d + (3 * 130 + sx + 1) * 36 + sq) = g3;                               \
            if (t < 32) *(frag16*)(d + (tl_r * 130 + tl_c) * 36 + tl_q) = gt;                \
        }

    LOADC(0);
    WRITEC(0);
    __syncthreads();

    #pragma unroll 1
    for (int c8 = 0; c8 < 8; ++c8) {
        int cur = c8 & 1;
        int ci0 = c8 * 32;
        if (c8 < 7) { LOADC(ci0 + 32); }   // in flight across compute (T14)

        const ushort* xs = Xs + cur * 18720;
        #pragma unroll
        for (int tap = 0; tap < 9; ++tap) {
            int ky = tap / 3, kx = tap % 3;
            frag16 av[4];
            #pragma unroll
            for (int m = 0; m < 4; ++m)
                av[m] = *(const frag16*)(wt + ((tap * 512 + cob + m * 16 + lanep) << 8) + ci0 + laneq);
            frag16 bfr[4];
            int rbase = ((row_w + ky) * 130 + col0 + kx + lanep) * 36 + laneq;
            #pragma unroll
            for (int n = 0; n < 4; ++n)
                bfr[n] = *(const frag16*)(xs + rbase + n * (16 * 36));
            #pragma unroll
            for (int m = 0; m < 4; ++m)
                #pragma unroll
                for (int n = 0; n < 4; ++n)
                    acc[m][n] = __builtin_amdgcn_mfma_f32_16x16x32_bf16(av[m], bfr[n], acc[m][n], 0, 0, 0);
        }
        __syncthreads();
        if (c8 < 7) { WRITEC(cur ^ 1); }
        __syncthreads();
    }

    // ---- epilogue: bias + tanh + per-class partial sums (part aliases Xs) ----
    float bv[4][4];
    #pragma unroll
    for (int m = 0; m < 4; ++m)
        #pragma unroll
        for (int r = 0; r < 4; ++r)
            bv[m][r] = bias[cob + m * 16 + hi * 4 + r];

    for (int e = t; e < S * 128; e += 512) part[e] = 0.f;
    __syncthreads();

    int y = y0 + row_w;
    int col = com * 64;                 // co offset within 128-part
    #pragma unroll
    for (int n = 0; n < 4; ++n) {
        int x = col0 + n * 16 + lanep;
        int s = lab[(b << 14) + (y << 7) + x];
        #pragma unroll
        for (int m = 0; m < 4; ++m)
            #pragma unroll
            for (int r = 0; r < 4; ++r)
                atomicAdd(&part[s * 128 + col + m * 16 + hi * 4 + r], tanhf(acc[m][n][r] + bv[m][r]));
    }
    __syncthreads();
    for (int e = t; e < S * 128; e += 512) {
        int s = e >> 7, cc = e & 127;
        atomicAdd(&sumbuf[((b * S + s) << 9) + ct * 128 + cc], part[e]);
    }
    #undef LOADC
    #undef WRITEC
}

// ---------------- finalize ----------------
__global__ LB void k_final(const float* __restrict__ sumbuf, const int* __restrict__ counts,
                           float* __restrict__ out) {
    int idx = blockIdx.x * 256 + threadIdx.x;   // 8*19*512
    int tt = idx >> 9;
    int s = tt % S, b = tt / S;
    int cnt = counts[b * S + s];
    out[idx] = cnt > 0 ? sumbuf[idx] / (float)cnt : 0.f;
}

extern "C" void kernel_launch(void* const* d_in, const int* in_sizes, int n_in,
                              void* d_out, int out_size, void* d_ws, size_t ws_size,
                              hipStream_t stream) {
    const float* input  = (const float*)d_in[0];
    const float* segmap = (const float*)d_in[1];
    const float* w1 = (const float*)d_in[2];  const float* b1 = (const float*)d_in[3];
    const float* w2 = (const float*)d_in[4];  const float* b2 = (const float*)d_in[5];
    const float* w3 = (const float*)d_in[6];  const float* b3 = (const float*)d_in[7];
    const float* w4 = (const float*)d_in[8];  const float* b4 = (const float*)d_in[9];
    const float* w5 = (const float*)d_in[10]; const float* b5 = (const float*)d_in[11];
    float* out = (float*)d_out;

    float* ws = (float*)d_ws;
    ushort* xl    = (ushort*)ws;                  // [8,128,128,256] bf16
    ushort* x1l   = (ushort*)(ws + 16777216);     // [8,256,256,32]
    ushort* x2l   = (ushort*)(ws + 25165824);     // [8,128,128,64]
    ushort* x3l   = (ushort*)(ws + 29360128);     // [8,64,64,128]
    float* sumbuf = ws + 31457280;                // 77,824
    float* mean   = ws + 31535104;                // 2,048
    float* istd   = ws + 31537152;                // 2,048
    int*   lab    = (int*)(ws + 31539200);        // 131,072
    int*   counts = (int*)(ws + 31670272);        // 256
    ushort* wt5   = (ushort*)(ws + 31670528);     // 1,179,648 bf16
    ushort* wt4t  = (ushort*)(ws + 32260352);     // 294,912 bf16
    ushort* wt2   = (ushort*)(ws + 32407808);     // 18,432 bf16
    ushort* wt3   = (ushort*)(ws + 32417024);     // 73,728 bf16
    float* psum   = ws + 32453888;                // 65,536
    float* pss    = ws + 32519424;                // 65,536

    hipMemsetAsync(sumbuf, 0, 77824 * sizeof(float), stream);
    hipMemsetAsync(counts, 0, 256 * sizeof(int), stream);

    k_wtall<<<6120, 256, 0, stream>>>(w2, w3, w4, w5, wt2, wt3, wt4t, wt5);
    // layer 1
    k_conv1cl<<<2048, 256, 0, stream>>>(input, w1, b1, x1l);
    k_stats_cl<32, 1024, 64><<<512, 256, 0, stream>>>(x1l, psum, pss);
    k_red_cl<32, 64, 65536><<<1, 256, 0, stream>>>(psum, pss, mean, istd);
    k_nl_cl<32, 65536><<<8192, 256, 0, stream>>>(x1l, mean, istd);
    // layer 2
    k_conv2m<<<1024, 256, 0, stream>>>(x1l, wt2, b2, x2l);
    k_stats_cl<64, 512, 32><<<256, 256, 0, stream>>>(x2l, psum, pss);
    k_red_cl<64, 32, 16384><<<2, 256, 0, stream>>>(psum, pss, mean, istd);
    k_nl_cl<64, 16384><<<4096, 256, 0, stream>>>(x2l, mean, istd);
    // layer 3
    k_conv3m<<<512, 256, 0, stream>>>(x2l, wt3, b3, x3l);
    k_stats_cl<128, 256, 16><<<128, 256, 0, stream>>>(x3l, psum, pss);
    k_red_cl<128, 16, 4096><<<4, 256, 0, stream>>>(psum, pss, mean, istd);
    k_nl_cl<128, 4096><<<2048, 256, 0, stream>>>(x3l, mean, istd);
    // layer 4 (transpose conv)
    k_convt4m<<<2048, 256, 0, stream>>>(x3l, wt4t, b4, xl);
    k_stats_cl<256, 512, 32><<<256, 256, 0, stream>>>(xl, psum, pss);
    k_red_cl<256, 32, 16384><<<8, 256, 0, stream>>>(psum, pss, mean, istd);
    k_nl_cl<256, 16384><<<16384, 256, 0, stream>>>(xl, mean, istd);
    // label map + counts
    k_label<<<512, 256, 0, stream>>>(segmap, lab, counts);
    // layer 5: MFMA implicit GEMM v2 fused with masked class-sum
    k_conv5m<<<2048, 512, 0, stream>>>(xl, wt5, b5, lab, sumbuf);
    // finalize
    k_final<<<304, 256, 0, stream>>>(sumbuf, counts, out);
}